// Round 14
// baseline (139.028 us; speedup 1.0000x reference)
//
#include <hip/hip_runtime.h>
#include <stdint.h>

typedef __attribute__((ext_vector_type(8))) short bf16x8;
typedef __attribute__((ext_vector_type(4))) float f32x4;
typedef __attribute__((ext_vector_type(4))) unsigned short us4;

#define DEV static __device__ __forceinline__

DEV unsigned short f2b(float f){
  union{float f; unsigned u;} x; x.f=f;
  unsigned r = x.u + 0x7fffu + ((x.u>>16)&1u);
  return (unsigned short)(r>>16);
}

DEV void glds16(const void* g, void* l){
  __builtin_amdgcn_global_load_lds((const __attribute__((address_space(1))) void*)g,
                                   (__attribute__((address_space(3))) void*)l, 16, 0, 0);
}

// ---------------- convert: f32 -> bf16 ----------------
__global__ __launch_bounds__(256) void convert_k(const float* __restrict__ in,
                                                 unsigned short* __restrict__ out, int n){
  int i = (blockIdx.x*256 + threadIdx.x)*8;
  if(i >= n) return;
  f32x4 a = *(const f32x4*)(in + i);
  f32x4 b = *(const f32x4*)(in + i + 4);
  us4 o0, o1;
  o0.x=f2b(a[0]); o0.y=f2b(a[1]); o0.z=f2b(a[2]); o0.w=f2b(a[3]);
  o1.x=f2b(b[0]); o1.y=f2b(b[1]); o1.z=f2b(b[2]); o1.w=f2b(b[3]);
  *(us4*)(out + i) = o0;
  *(us4*)(out + i + 4) = o1;
}

// ---------------- transpose+convert: in f32 [K][N] -> out bf16 [N][K] ----------------
__global__ __launch_bounds__(256) void transpose_k(const float* __restrict__ in,
                                                   unsigned short* __restrict__ out,
                                                   int ldin, int ldout){
  __shared__ __attribute__((aligned(16))) unsigned short tile[64][72];
  const int c0 = blockIdx.x*64, r0 = blockIdx.y*64;
  const int t = threadIdx.x;
  const int tr = t>>4, tc4 = (t&15)*4;
  #pragma unroll
  for(int j=0;j<4;j++){
    int r = tr + j*16;
    f32x4 v = *(const f32x4*)(in + (size_t)(r0+r)*ldin + c0 + tc4);
    tile[r][tc4+0] = f2b(v[0]);
    tile[r][tc4+1] = f2b(v[1]);
    tile[r][tc4+2] = f2b(v[2]);
    tile[r][tc4+3] = f2b(v[3]);
  }
  __syncthreads();
  #pragma unroll
  for(int j=0;j<4;j++){
    int r = tr + j*16;
    us4 v;
    v.x = tile[tc4+0][r];
    v.y = tile[tc4+1][r];
    v.z = tile[tc4+2][r];
    v.w = tile[tc4+3][r];
    *(us4*)(out + (size_t)(c0+r)*ldout + r0 + tc4) = v;
  }
}

// ---------------- shared GEMM core (R11-exact): BK=64, single-buffered ----------------
#define BK 64

DEV void gemm_core_128(const unsigned short* __restrict__ A,
                       const unsigned short* __restrict__ Bt,
                       int K, int rowA0, int rowB0,
                       unsigned short* As, unsigned short* Bs, f32x4 acc[4][4])
{
  const int t = threadIdx.x;
  const int lane = t & 63;
  const int wid  = t >> 6;
  const int wm = wid >> 1, wn = wid & 1;
  const f32x4 Z = {0.f,0.f,0.f,0.f};

  #pragma unroll
  for(int m=0;m<4;m++)
    #pragma unroll
    for(int n=0;n<4;n++) acc[m][n] = Z;

  for(int kt=0; kt<K; kt+=BK){
    __syncthreads();
    #pragma unroll
    for(int j=0;j<4;j++){
      int idx = t + 256*j;          // 16B chunk index, 1024 chunks = 128 rows x 8
      int row = idx >> 3;
      int ls  = (idx & 7) ^ (row & 7);
      glds16(A + (size_t)(rowA0 + row)*K + kt + ls*8, As + (size_t)(wid*64 + 256*j)*8);
    }
    #pragma unroll
    for(int j=0;j<4;j++){
      int idx = t + 256*j;
      int row = idx >> 3;
      int ls  = (idx & 7) ^ (row & 7);
      glds16(Bt + (size_t)(rowB0 + row)*K + kt + ls*8, Bs + (size_t)(wid*64 + 256*j)*8);
    }
    __syncthreads();
    #pragma unroll
    for(int ks=0; ks<2; ks++){
      bf16x8 af[4], bfr[4];
      #pragma unroll
      for(int m=0;m<4;m++){
        int row = wm*64 + m*16 + (lane&15);
        int sl  = (ks*4 + (lane>>4)) ^ (row&7);
        af[m] = *(const bf16x8*)(As + row*64 + sl*8);
      }
      #pragma unroll
      for(int n=0;n<4;n++){
        int row = wn*64 + n*16 + (lane&15);
        int sl  = (ks*4 + (lane>>4)) ^ (row&7);
        bfr[n] = *(const bf16x8*)(Bs + row*64 + sl*8);
      }
      #pragma unroll
      for(int m=0;m<4;m++)
        #pragma unroll
        for(int n=0;n<4;n++)
          acc[m][n] = __builtin_amdgcn_mfma_f32_16x16x32_bf16(af[m], bfr[n], acc[m][n], 0, 0, 0);
    }
  }
}

// ---------------- GEMM1: qkv = xb @ w_qkv + b -> q,k [bh][n][d]; V stored TRANSPOSED ----
__global__ __launch_bounds__(256) void gemm_qkv(const unsigned short* __restrict__ xb,
                                                const unsigned short* __restrict__ Wt,
                                                const float* __restrict__ bqkv,
                                                unsigned short* __restrict__ q,
                                                unsigned short* __restrict__ k,
                                                unsigned short* __restrict__ vt)
{
  __shared__ __attribute__((aligned(16))) unsigned short SMEM[2*128*BK];  // 32KB
  unsigned short* As = SMEM;
  unsigned short* Bs = SMEM + 128*BK;
  f32x4 acc[4][4];
  const int bm = blockIdx.x, bn = blockIdx.y;
  gemm_core_128(xb, Wt, 1024, bm*128, bn*128, As, Bs, acc);
  __syncthreads();   // all waves done reading As/Bs before epilogue reuse

  const int t = threadIdx.x, lane = t&63, wid = t>>6, wm = wid>>1, wn = wid&1;
  const int col0 = bn*128 + wn*64;          // 64-aligned -> one source (q/k/v), one head
  const int three = col0 >> 10;
  const int h = (col0>>6)&15;
  const int row0 = bm*128 + wm*64;          // 64 tokens, within one batch
  const int bb = row0 >> 11, nn0 = row0 & 2047;
  const size_t bh = (size_t)(bb*16 + h);

  if(three < 2){
    unsigned short* dst = (three==0) ? q : k;
    #pragma unroll
    for(int m=0;m<4;m++)
      #pragma unroll
      for(int n=0;n<4;n++){
        int d = (col0 & 63) + n*16 + (lane&15);        // 0..63
        float bias = bqkv[col0 + n*16 + (lane&15)];
        #pragma unroll
        for(int r=0;r<4;r++){
          int nn = nn0 + m*16 + (lane>>4)*4 + r;
          dst[(bh*2048 + nn)*64 + d] = f2b(acc[m][n][r] + bias);
        }
      }
  } else {
    // V: stage wave tile as [d][n] in own LDS region, then coalesced store
    unsigned short* ep = SMEM + wid*4096;   // 64*64 elems = 8KB
    #pragma unroll
    for(int n=0;n<4;n++){
      int dl = n*16 + (lane&15);
      float bias = bqkv[col0 + dl];
      #pragma unroll
      for(int m=0;m<4;m++){
        int nl = m*16 + (lane>>4)*4;
        unsigned w0, w1;
        float a0 = acc[m][n][0] + bias, a1 = acc[m][n][1] + bias;
        float a2 = acc[m][n][2] + bias, a3 = acc[m][n][3] + bias;
        asm("v_cvt_pk_bf16_f32 %0, %1, %2" : "=v"(w0) : "v"(a0), "v"(a1));
        asm("v_cvt_pk_bf16_f32 %0, %1, %2" : "=v"(w1) : "v"(a2), "v"(a3));
        *(unsigned*)(ep + dl*64 + nl)     = w0;
        *(unsigned*)(ep + dl*64 + nl + 2) = w1;
      }
    }
    // same-wave readback (program-order DS within a wave; compiler inserts waits)
    #pragma unroll
    for(int p=0;p<16;p++){
      int dl = p*4 + (lane>>4);
      us4 vv = *(const us4*)(ep + dl*64 + (lane&15)*4);
      *(us4*)(vt + (bh*64 + dl)*2048 + nn0 + (lane&15)*4) = vv;
    }
  }
}

// ---------------- GEMM2: out(f32) = y @ w_proj + b ----------------
__global__ __launch_bounds__(256) void gemm_proj(const unsigned short* __restrict__ y,
                                                 const unsigned short* __restrict__ Wt,
                                                 const float* __restrict__ bp,
                                                 float* __restrict__ out)
{
  __shared__ __attribute__((aligned(16))) unsigned short As[128*BK];
  __shared__ __attribute__((aligned(16))) unsigned short Bs[128*BK];
  f32x4 acc[4][4];
  const int bm = blockIdx.x, bn = blockIdx.y;
  gemm_core_128(y, Wt, 1024, bm*128, bn*128, As, Bs, acc);

  const int t = threadIdx.x, lane = t&63, wid = t>>6, wm = wid>>1, wn = wid&1;
  #pragma unroll
  for(int m=0;m<4;m++)
    #pragma unroll
    for(int n=0;n<4;n++){
      int col = bn*128 + wn*64 + n*16 + (lane&15);
      float bias = bp[col];
      #pragma unroll
      for(int r=0;r<4;r++){
        int row = bm*128 + wm*64 + m*16 + (lane>>4)*4 + r;
        out[(size_t)row*1024 + col] = acc[m][n][r] + bias;
      }
    }
}

// ---------------- flash attention v10: 32 q-rows/WAVE, 2-wave blocks, hoisted bv ----
// Block = 128 threads (2 waves), 64 q-rows; grid (32,32)=1024 -> 4 blocks/CU at
// LDS 40KB. Per wave-iter LDS reads: bk 8 (shared by both m) + bv 8 (hoisted to
// regs, reused across m) + pa 4 = 20 for 32 q-rows (v6: 18 for 16) -> ~44% less
// LDS-pipe traffic per q-row. All numeric paths identical to the proven v6.
__global__ __launch_bounds__(128) void attn_k(const unsigned short* __restrict__ qg,
                                              const unsigned short* __restrict__ kg,
                                              const unsigned short* __restrict__ vtg,
                                              unsigned short* __restrict__ y)
{
  __shared__ __attribute__((aligned(16))) unsigned short Ks[2][64*64];    // [kv][d] swizzled
  __shared__ __attribute__((aligned(16))) unsigned short VT[2][64*64];    // [d][kv] swizzled
  __shared__ __attribute__((aligned(16))) unsigned short Ps[2][2][16*64]; // [wave][m] P^T, swizzled

  const int bh = blockIdx.x;      // b*16 + h
  const int qt = blockIdx.y;      // 0..31
  const int b  = bh >> 4, h = bh & 15;
  const unsigned short* qh = qg  + (size_t)bh*2048*64;
  const unsigned short* kh = kg  + (size_t)bh*2048*64;
  const unsigned short* vh = vtg + (size_t)bh*64*2048;

  const int t = threadIdx.x, lane = t & 63, wid = t >> 6;   // wid in {0,1}
  const int q0 = qt*64 + wid*32;
  const int lq = lane & 15;
  const int lh = lane >> 4;                 // 16-lane group 0..3
  const float C1 = 0.18033688011112042f;    // (1/8) * log2(e)

  // Q fragments: two 16-row m-subtiles per wave
  bf16x8 aq[2][2];
  #pragma unroll
  for(int m=0;m<2;m++)
    #pragma unroll
    for(int ks=0;ks<2;ks++){
      int row = q0 + m*16 + lq;
      aq[m][ks] = *(const bf16x8*)(qh + (size_t)row*64 + ks*32 + lh*8);
    }

  const f32x4 Z = {0.f,0.f,0.f,0.f};
  f32x4 accT[2][4];                 // O^T tiles: [m][d-subtile]
  #pragma unroll
  for(int m=0;m<2;m++)
    #pragma unroll
    for(int df=0;df<4;df++) accT[m][df] = Z;
  float lpart[2] = {0.f, 0.f};

  // staging: 128 threads x 4 chunks cover the 512 16B chunks of each 8KB tile
#define STAGE(SRC, DSTBASE, ROWSTRIDE, COLOFF) do{                             \
    _Pragma("unroll")                                                          \
    for(int j=0;j<4;j++){                                                      \
      int idx = t + 128*j;                                                     \
      int row = idx >> 3;                                                      \
      int ls  = (idx & 7) ^ (row & 7);                                         \
      glds16((SRC) + (size_t)row*(ROWSTRIDE) + (COLOFF) + ls*8,                \
             (DSTBASE) + (size_t)(wid*64 + 128*j)*8);                          \
    }}while(0)

  // prologue: stage tile 0
  STAGE(kh, &Ks[0][0], 64, 0);
  STAGE(vh, &VT[0][0], 2048, 0);
  __syncthreads();

  for(int it=0; it<32; ++it){
    const int cur = it & 1, nxt = cur ^ 1;
    if(it < 31){
      int kvn = (it+1)*64;
      STAGE(kh + (size_t)kvn*64, &Ks[nxt][0], 64, 0);
      STAGE(vh, &VT[nxt][0], 2048, kvn);
    }

    // S^T = mfma(K, Q) for both m (bk shared)
    f32x4 st[2][4];
    #pragma unroll
    for(int m=0;m<2;m++)
      #pragma unroll
      for(int nc=0;nc<4;nc++) st[m][nc] = Z;
    __builtin_amdgcn_s_setprio(1);
    #pragma unroll
    for(int ks=0;ks<2;ks++){
      bf16x8 bk[4];
      #pragma unroll
      for(int nc=0;nc<4;nc++){
        int kvr = nc*16 + lq;
        int sl  = (ks*4 + lh) ^ (kvr&7);
        bk[nc] = *(const bf16x8*)(&Ks[cur][0] + kvr*64 + sl*8);
      }
      #pragma unroll
      for(int m=0;m<2;m++)
        #pragma unroll
        for(int nc=0;nc<4;nc++)
          st[m][nc] = __builtin_amdgcn_mfma_f32_16x16x32_bf16(bk[nc], aq[m][ks], st[m][nc], 0,0,0);
    }
    __builtin_amdgcn_s_setprio(0);

    // softmax numerators for both m -> per-(wave,m) swizzled Ps
    #pragma unroll
    for(int m=0;m<2;m++){
      float rs = 0.f;
      unsigned short* pr = &Ps[wid][m][0] + lq*64;   // 128B row
      #pragma unroll
      for(int nc=0;nc<4;nc++){
        float p0 = __builtin_amdgcn_exp2f(st[m][nc][0]*C1);
        float p1 = __builtin_amdgcn_exp2f(st[m][nc][1]*C1);
        float p2 = __builtin_amdgcn_exp2f(st[m][nc][2]*C1);
        float p3 = __builtin_amdgcn_exp2f(st[m][nc][3]*C1);
        rs += (p0+p1)+(p2+p3);
        unsigned w0, w1;
        asm("v_cvt_pk_bf16_f32 %0, %1, %2" : "=v"(w0) : "v"(p0), "v"(p1));
        asm("v_cvt_pk_bf16_f32 %0, %1, %2" : "=v"(w1) : "v"(p2), "v"(p3));
        int g    = 2*nc + (lh>>1);
        int phys = g ^ (lane&7);
        unsigned* dst = (unsigned*)(pr + phys*8 + (lh&1)*4);
        dst[0] = w0; dst[1] = w1;
      }
      lpart[m] += rs;
    }

    // PV: bv hoisted once per ks, reused for both m
    __builtin_amdgcn_s_setprio(1);
    #pragma unroll
    for(int ks=0;ks<2;ks++){
      bf16x8 bv[4];
      #pragma unroll
      for(int df=0;df<4;df++){
        int dr = df*16 + lq;
        int sl = (ks*4 + lh) ^ (dr&7);
        bv[df] = *(const bf16x8*)(&VT[cur][0] + dr*64 + sl*8);
      }
      #pragma unroll
      for(int m=0;m<2;m++){
        bf16x8 pa;
        int g    = 4*ks + lh;
        int phys = g ^ (lane&7);
        pa = *(const bf16x8*)(&Ps[wid][m][0] + lq*64 + phys*8);
        #pragma unroll
        for(int df=0;df<4;df++)
          accT[m][df] = __builtin_amdgcn_mfma_f32_16x16x32_bf16(bv[df], pa, accT[m][df], 0,0,0);
      }
    }
    __builtin_amdgcn_s_setprio(0);

    __syncthreads();   // drains this wave's prefetch glds + all waves' LDS reads of cur
  }
#undef STAGE

  // epilogue: per-m cross-lane sum, normalize, store
  #pragma unroll
  for(int m=0;m<2;m++){
    float ls = lpart[m];
    ls += __shfl_xor(ls, 16, 64);
    ls += __shfl_xor(ls, 32, 64);
    float rl = 1.0f / ls;
    int row = q0 + m*16 + lq;
    #pragma unroll
    for(int df=0;df<4;df++){
      us4 o;
      o.x = f2b(accT[m][df][0] * rl);
      o.y = f2b(accT[m][df][1] * rl);
      o.z = f2b(accT[m][df][2] * rl);
      o.w = f2b(accT[m][df][3] * rl);
      *(us4*)(y + ((size_t)b*2048 + row)*1024 + h*64 + df*16 + lh*4) = o;
    }
  }
}

extern "C" void kernel_launch(void* const* d_in, const int* in_sizes, int n_in,
                              void* d_out, int out_size, void* d_ws, size_t ws_size,
                              hipStream_t stream) {
  const float* x     = (const float*)d_in[0];
  const float* wqkv  = (const float*)d_in[1];
  const float* bqkv  = (const float*)d_in[2];
  const float* wproj = (const float*)d_in[3];
  const float* bproj = (const float*)d_in[4];
  float* out = (float*)d_out;

  char* ws = (char*)d_ws;
  unsigned short* Wt1 = (unsigned short*)ws;  ws += (size_t)3072*1024*2;
  unsigned short* Wt2 = (unsigned short*)ws;  ws += (size_t)1024*1024*2;
  unsigned short* xb  = (unsigned short*)ws;  ws += (size_t)2*2048*1024*2;
  unsigned short* q   = (unsigned short*)ws;  ws += (size_t)2*16*2048*64*2;
  unsigned short* k   = (unsigned short*)ws;  ws += (size_t)2*16*2048*64*2;
  unsigned short* vt  = (unsigned short*)ws;  ws += (size_t)2*16*2048*64*2;
  unsigned short* y   = (unsigned short*)ws;  ws += (size_t)2*2048*1024*2;

  convert_k  <<<2048, 256, 0, stream>>>(x, xb, 2*2048*1024);
  transpose_k<<<dim3(48,16), 256, 0, stream>>>(wqkv,  Wt1, 3072, 1024);
  transpose_k<<<dim3(16,16), 256, 0, stream>>>(wproj, Wt2, 1024, 1024);
  gemm_qkv  <<<dim3(32,24), 256, 0, stream>>>(xb, Wt1, bqkv, q, k, vt);
  attn_k    <<<dim3(32,32), 128, 0, stream>>>(q, k, vt, y);
  gemm_proj <<<dim3(32, 8), 256, 0, stream>>>(y, Wt2, bproj, out);
}

// Round 15
// 132.237 us; speedup vs baseline: 1.0514x; 1.0514x over previous
//
#include <hip/hip_runtime.h>
#include <stdint.h>

typedef __attribute__((ext_vector_type(8))) short bf16x8;
typedef __attribute__((ext_vector_type(4))) float f32x4;
typedef __attribute__((ext_vector_type(4))) unsigned short us4;

#define DEV static __device__ __forceinline__

DEV unsigned short f2b(float f){
  union{float f; unsigned u;} x; x.f=f;
  unsigned r = x.u + 0x7fffu + ((x.u>>16)&1u);
  return (unsigned short)(r>>16);
}

DEV void glds16(const void* g, void* l){
  __builtin_amdgcn_global_load_lds((const __attribute__((address_space(1))) void*)g,
                                   (__attribute__((address_space(3))) void*)l, 16, 0, 0);
}

// ---------------- convert: f32 -> bf16 ----------------
__global__ __launch_bounds__(256) void convert_k(const float* __restrict__ in,
                                                 unsigned short* __restrict__ out, int n){
  int i = (blockIdx.x*256 + threadIdx.x)*8;
  if(i >= n) return;
  f32x4 a = *(const f32x4*)(in + i);
  f32x4 b = *(const f32x4*)(in + i + 4);
  us4 o0, o1;
  o0.x=f2b(a[0]); o0.y=f2b(a[1]); o0.z=f2b(a[2]); o0.w=f2b(a[3]);
  o1.x=f2b(b[0]); o1.y=f2b(b[1]); o1.z=f2b(b[2]); o1.w=f2b(b[3]);
  *(us4*)(out + i) = o0;
  *(us4*)(out + i + 4) = o1;
}

// ------- merged transpose+convert: w_qkv (x<48) and w_proj (x>=48) in ONE launch -------
// f32 [K][N] -> bf16 [N][K], 64x64 tiles through padded LDS.
__global__ __launch_bounds__(256) void transpose2_k(const float* __restrict__ in1,
                                                    unsigned short* __restrict__ out1,
                                                    const float* __restrict__ in2,
                                                    unsigned short* __restrict__ out2){
  __shared__ __attribute__((aligned(16))) unsigned short tile[64][72];
  const int bx = blockIdx.x;
  const float* in;  unsigned short* out;  int ldin, ldout, c0;
  if(bx < 48){ in = in1; out = out1; ldin = 3072; ldout = 1024; c0 = bx*64; }
  else       { in = in2; out = out2; ldin = 1024; ldout = 1024; c0 = (bx-48)*64; }
  const int r0 = blockIdx.y*64;
  const int t = threadIdx.x;
  const int tr = t>>4, tc4 = (t&15)*4;
  #pragma unroll
  for(int j=0;j<4;j++){
    int r = tr + j*16;
    f32x4 v = *(const f32x4*)(in + (size_t)(r0+r)*ldin + c0 + tc4);
    tile[r][tc4+0] = f2b(v[0]);
    tile[r][tc4+1] = f2b(v[1]);
    tile[r][tc4+2] = f2b(v[2]);
    tile[r][tc4+3] = f2b(v[3]);
  }
  __syncthreads();
  #pragma unroll
  for(int j=0;j<4;j++){
    int r = tr + j*16;
    us4 v;
    v.x = tile[tc4+0][r];
    v.y = tile[tc4+1][r];
    v.z = tile[tc4+2][r];
    v.w = tile[tc4+3][r];
    *(us4*)(out + (size_t)(c0+r)*ldout + r0 + tc4) = v;
  }
}

// ---------------- shared GEMM core (R11-exact): BK=64, single-buffered ----------------
#define BK 64

DEV void gemm_core_128(const unsigned short* __restrict__ A,
                       const unsigned short* __restrict__ Bt,
                       int K, int rowA0, int rowB0,
                       unsigned short* As, unsigned short* Bs, f32x4 acc[4][4])
{
  const int t = threadIdx.x;
  const int lane = t & 63;
  const int wid  = t >> 6;
  const int wm = wid >> 1, wn = wid & 1;
  const f32x4 Z = {0.f,0.f,0.f,0.f};

  #pragma unroll
  for(int m=0;m<4;m++)
    #pragma unroll
    for(int n=0;n<4;n++) acc[m][n] = Z;

  for(int kt=0; kt<K; kt+=BK){
    __syncthreads();
    #pragma unroll
    for(int j=0;j<4;j++){
      int idx = t + 256*j;          // 16B chunk index, 1024 chunks = 128 rows x 8
      int row = idx >> 3;
      int ls  = (idx & 7) ^ (row & 7);
      glds16(A + (size_t)(rowA0 + row)*K + kt + ls*8, As + (size_t)(wid*64 + 256*j)*8);
    }
    #pragma unroll
    for(int j=0;j<4;j++){
      int idx = t + 256*j;
      int row = idx >> 3;
      int ls  = (idx & 7) ^ (row & 7);
      glds16(Bt + (size_t)(rowB0 + row)*K + kt + ls*8, Bs + (size_t)(wid*64 + 256*j)*8);
    }
    __syncthreads();
    #pragma unroll
    for(int ks=0; ks<2; ks++){
      bf16x8 af[4], bfr[4];
      #pragma unroll
      for(int m=0;m<4;m++){
        int row = wm*64 + m*16 + (lane&15);
        int sl  = (ks*4 + (lane>>4)) ^ (row&7);
        af[m] = *(const bf16x8*)(As + row*64 + sl*8);
      }
      #pragma unroll
      for(int n=0;n<4;n++){
        int row = wn*64 + n*16 + (lane&15);
        int sl  = (ks*4 + (lane>>4)) ^ (row&7);
        bfr[n] = *(const bf16x8*)(Bs + row*64 + sl*8);
      }
      #pragma unroll
      for(int m=0;m<4;m++)
        #pragma unroll
        for(int n=0;n<4;n++)
          acc[m][n] = __builtin_amdgcn_mfma_f32_16x16x32_bf16(af[m], bfr[n], acc[m][n], 0, 0, 0);
    }
  }
}

// ---------------- GEMM1: qkv = xb @ w_qkv + b -> q,k [bh][n][d]; V stored TRANSPOSED ----
__global__ __launch_bounds__(256) void gemm_qkv(const unsigned short* __restrict__ xb,
                                                const unsigned short* __restrict__ Wt,
                                                const float* __restrict__ bqkv,
                                                unsigned short* __restrict__ q,
                                                unsigned short* __restrict__ k,
                                                unsigned short* __restrict__ vt)
{
  __shared__ __attribute__((aligned(16))) unsigned short SMEM[2*128*BK];  // 32KB
  unsigned short* As = SMEM;
  unsigned short* Bs = SMEM + 128*BK;
  f32x4 acc[4][4];
  const int bm = blockIdx.x, bn = blockIdx.y;
  gemm_core_128(xb, Wt, 1024, bm*128, bn*128, As, Bs, acc);
  __syncthreads();   // all waves done reading As/Bs before epilogue reuse

  const int t = threadIdx.x, lane = t&63, wid = t>>6, wm = wid>>1, wn = wid&1;
  const int col0 = bn*128 + wn*64;          // 64-aligned -> one source (q/k/v), one head
  const int three = col0 >> 10;
  const int h = (col0>>6)&15;
  const int row0 = bm*128 + wm*64;          // 64 tokens, within one batch
  const int bb = row0 >> 11, nn0 = row0 & 2047;
  const size_t bh = (size_t)(bb*16 + h);

  if(three < 2){
    unsigned short* dst = (three==0) ? q : k;
    #pragma unroll
    for(int m=0;m<4;m++)
      #pragma unroll
      for(int n=0;n<4;n++){
        int d = (col0 & 63) + n*16 + (lane&15);        // 0..63
        float bias = bqkv[col0 + n*16 + (lane&15)];
        #pragma unroll
        for(int r=0;r<4;r++){
          int nn = nn0 + m*16 + (lane>>4)*4 + r;
          dst[(bh*2048 + nn)*64 + d] = f2b(acc[m][n][r] + bias);
        }
      }
  } else {
    // V: stage wave tile as [d][n] in own LDS region, then coalesced store
    unsigned short* ep = SMEM + wid*4096;   // 64*64 elems = 8KB
    #pragma unroll
    for(int n=0;n<4;n++){
      int dl = n*16 + (lane&15);
      float bias = bqkv[col0 + dl];
      #pragma unroll
      for(int m=0;m<4;m++){
        int nl = m*16 + (lane>>4)*4;
        unsigned w0, w1;
        float a0 = acc[m][n][0] + bias, a1 = acc[m][n][1] + bias;
        float a2 = acc[m][n][2] + bias, a3 = acc[m][n][3] + bias;
        asm("v_cvt_pk_bf16_f32 %0, %1, %2" : "=v"(w0) : "v"(a0), "v"(a1));
        asm("v_cvt_pk_bf16_f32 %0, %1, %2" : "=v"(w1) : "v"(a2), "v"(a3));
        *(unsigned*)(ep + dl*64 + nl)     = w0;
        *(unsigned*)(ep + dl*64 + nl + 2) = w1;
      }
    }
    // same-wave readback (program-order DS within a wave; compiler inserts waits)
    #pragma unroll
    for(int p=0;p<16;p++){
      int dl = p*4 + (lane>>4);
      us4 vv = *(const us4*)(ep + dl*64 + (lane&15)*4);
      *(us4*)(vt + (bh*64 + dl)*2048 + nn0 + (lane&15)*4) = vv;
    }
  }
}

// ---------------- GEMM2: out(f32) = y @ w_proj + b ----------------
__global__ __launch_bounds__(256) void gemm_proj(const unsigned short* __restrict__ y,
                                                 const unsigned short* __restrict__ Wt,
                                                 const float* __restrict__ bp,
                                                 float* __restrict__ out)
{
  __shared__ __attribute__((aligned(16))) unsigned short As[128*BK];
  __shared__ __attribute__((aligned(16))) unsigned short Bs[128*BK];
  f32x4 acc[4][4];
  const int bm = blockIdx.x, bn = blockIdx.y;
  gemm_core_128(y, Wt, 1024, bm*128, bn*128, As, Bs, acc);

  const int t = threadIdx.x, lane = t&63, wid = t>>6, wm = wid>>1, wn = wid&1;
  #pragma unroll
  for(int m=0;m<4;m++)
    #pragma unroll
    for(int n=0;n<4;n++){
      int col = bn*128 + wn*64 + n*16 + (lane&15);
      float bias = bp[col];
      #pragma unroll
      for(int r=0;r<4;r++){
        int row = bm*128 + wm*64 + m*16 + (lane>>4)*4 + r;
        out[(size_t)row*1024 + col] = acc[m][n][r] + bias;
      }
    }
}

// ---------------- flash attention v6 (R13-exact, proven 62us): 64 q-rows/block ----
__global__ __launch_bounds__(256, 4) void attn_k(const unsigned short* __restrict__ qg,
                                                 const unsigned short* __restrict__ kg,
                                                 const unsigned short* __restrict__ vtg,
                                                 unsigned short* __restrict__ y)
{
  __shared__ __attribute__((aligned(16))) unsigned short Ks[2][64*64];  // [kv][d] swizzled
  __shared__ __attribute__((aligned(16))) unsigned short VT[2][64*64];  // [d][kv] swizzled
  __shared__ __attribute__((aligned(16))) unsigned short Ps[4][16*64];  // per-wave P^T, swizzled

  const int bh = blockIdx.x;      // b*16 + h
  const int qt = blockIdx.y;      // 0..31
  const int b  = bh >> 4, h = bh & 15;
  const unsigned short* qh = qg  + (size_t)bh*2048*64;
  const unsigned short* kh = kg  + (size_t)bh*2048*64;
  const unsigned short* vh = vtg + (size_t)bh*64*2048;

  const int t = threadIdx.x, lane = t & 63, wid = t >> 6;
  const int q0 = qt*64 + wid*16;
  const int lq = lane & 15;
  const int lh = lane >> 4;                 // 16-lane group 0..3
  const float C1 = 0.18033688011112042f;    // (1/8) * log2(e)

  // Q fragments (B-operand pattern) held in registers
  bf16x8 aq[2];
  #pragma unroll
  for(int ks=0;ks<2;ks++){
    int row = q0 + lq;
    aq[ks] = *(const bf16x8*)(qh + (size_t)row*64 + ks*32 + lh*8);
  }

  const f32x4 Z = {0.f,0.f,0.f,0.f};
  f32x4 accT[4];                    // O^T tiles per d-subtile
  #pragma unroll
  for(int df=0;df<4;df++) accT[df] = Z;
  float lpart = 0.f;                // per-lane partial row-sum

  // prologue: stage tile 0 into buffer 0
  #pragma unroll
  for(int j=0;j<2;j++){
    int idx = t + 256*j;
    int row = idx >> 3;
    int ls  = (idx & 7) ^ (row & 7);
    glds16(kh + (size_t)row*64 + ls*8, &Ks[0][0] + (wid*64 + 256*j)*8);
    glds16(vh + (size_t)row*2048 + ls*8, &VT[0][0] + (wid*64 + 256*j)*8);
  }
  __syncthreads();

  for(int it=0; it<32; ++it){
    const int cur = it & 1, nxt = cur ^ 1;
    // prefetch next tile (loads stay in flight across the compute phase)
    if(it < 31){
      int kvn = (it+1)*64;
      #pragma unroll
      for(int j=0;j<2;j++){
        int idx = t + 256*j;
        int row = idx >> 3;
        int ls  = (idx & 7) ^ (row & 7);
        glds16(kh + (size_t)(kvn+row)*64 + ls*8, &Ks[nxt][0] + (wid*64 + 256*j)*8);
        glds16(vh + (size_t)row*2048 + kvn + ls*8, &VT[nxt][0] + (wid*64 + 256*j)*8);
      }
    }

    // S^T = mfma(K, Q)
    f32x4 st[4];
    #pragma unroll
    for(int nc=0;nc<4;nc++) st[nc] = Z;
    __builtin_amdgcn_s_setprio(1);
    #pragma unroll
    for(int ks=0;ks<2;ks++){
      bf16x8 bk[4];
      #pragma unroll
      for(int nc=0;nc<4;nc++){
        int kvr = nc*16 + lq;
        int sl  = (ks*4 + lh) ^ (kvr&7);
        bk[nc] = *(const bf16x8*)(&Ks[cur][0] + kvr*64 + sl*8);
      }
      #pragma unroll
      for(int nc=0;nc<4;nc++)
        st[nc] = __builtin_amdgcn_mfma_f32_16x16x32_bf16(bk[nc], aq[ks], st[nc], 0,0,0);
    }
    __builtin_amdgcn_s_setprio(0);

    // softmax numerator p = 2^(s*C1): raw v_exp + cvt_pk pack + swizzled 8B LDS write
    {
      float rs = 0.f;
      unsigned short* pr = &Ps[wid][0] + lq*64;   // 128B row
      #pragma unroll
      for(int nc=0;nc<4;nc++){
        float p0 = __builtin_amdgcn_exp2f(st[nc][0]*C1);
        float p1 = __builtin_amdgcn_exp2f(st[nc][1]*C1);
        float p2 = __builtin_amdgcn_exp2f(st[nc][2]*C1);
        float p3 = __builtin_amdgcn_exp2f(st[nc][3]*C1);
        rs += (p0+p1)+(p2+p3);
        unsigned w0, w1;
        asm("v_cvt_pk_bf16_f32 %0, %1, %2" : "=v"(w0) : "v"(p0), "v"(p1));
        asm("v_cvt_pk_bf16_f32 %0, %1, %2" : "=v"(w1) : "v"(p2), "v"(p3));
        int g    = 2*nc + (lh>>1);
        int phys = g ^ (lane&7);
        unsigned* dst = (unsigned*)(pr + phys*8 + (lh&1)*4);
        dst[0] = w0; dst[1] = w1;
      }
      lpart += rs;
    }

    // O^T += mfma(V^T, P^T)  (own-wave Ps region; same-wave DS ordering)
    __builtin_amdgcn_s_setprio(1);
    #pragma unroll
    for(int ks=0;ks<2;ks++){
      bf16x8 bv[4], pa;
      #pragma unroll
      for(int df=0;df<4;df++){
        int dr = df*16 + lq;
        int sl = (ks*4 + lh) ^ (dr&7);
        bv[df] = *(const bf16x8*)(&VT[cur][0] + dr*64 + sl*8);
      }
      {
        int g    = 4*ks + lh;
        int phys = g ^ (lane&7);
        pa = *(const bf16x8*)(&Ps[wid][0] + lq*64 + phys*8);
      }
      #pragma unroll
      for(int df=0;df<4;df++)
        accT[df] = __builtin_amdgcn_mfma_f32_16x16x32_bf16(bv[df], pa, accT[df], 0,0,0);
    }
    __builtin_amdgcn_s_setprio(0);

    __syncthreads();   // drains this wave's prefetch glds + all waves' LDS reads of cur
  }

  // epilogue: one cross-lane sum, then normalize + store
  float ls = lpart;
  ls += __shfl_xor(ls, 16, 64);
  ls += __shfl_xor(ls, 32, 64);
  float rl = 1.0f / ls;
  int row = q0 + lq;
  #pragma unroll
  for(int df=0;df<4;df++){
    us4 o;
    o.x = f2b(accT[df][0] * rl);
    o.y = f2b(accT[df][1] * rl);
    o.z = f2b(accT[df][2] * rl);
    o.w = f2b(accT[df][3] * rl);
    *(us4*)(y + ((size_t)b*2048 + row)*1024 + h*64 + df*16 + lh*4) = o;
  }
}

extern "C" void kernel_launch(void* const* d_in, const int* in_sizes, int n_in,
                              void* d_out, int out_size, void* d_ws, size_t ws_size,
                              hipStream_t stream) {
  const float* x     = (const float*)d_in[0];
  const float* wqkv  = (const float*)d_in[1];
  const float* bqkv  = (const float*)d_in[2];
  const float* wproj = (const float*)d_in[3];
  const float* bproj = (const float*)d_in[4];
  float* out = (float*)d_out;

  char* ws = (char*)d_ws;
  unsigned short* Wt1 = (unsigned short*)ws;  ws += (size_t)3072*1024*2;
  unsigned short* Wt2 = (unsigned short*)ws;  ws += (size_t)1024*1024*2;
  unsigned short* xb  = (unsigned short*)ws;  ws += (size_t)2*2048*1024*2;
  unsigned short* q   = (unsigned short*)ws;  ws += (size_t)2*16*2048*64*2;
  unsigned short* k   = (unsigned short*)ws;  ws += (size_t)2*16*2048*64*2;
  unsigned short* vt  = (unsigned short*)ws;  ws += (size_t)2*16*2048*64*2;
  unsigned short* y   = (unsigned short*)ws;  ws += (size_t)2*2048*1024*2;

  convert_k   <<<2048, 256, 0, stream>>>(x, xb, 2*2048*1024);
  transpose2_k<<<dim3(64,16), 256, 0, stream>>>(wqkv, Wt1, wproj, Wt2);
  gemm_qkv   <<<dim3(32,24), 256, 0, stream>>>(xb, Wt1, bqkv, q, k, vt);
  attn_k     <<<dim3(32,32), 256, 0, stream>>>(q, k, vt, y);
  gemm_proj  <<<dim3(32, 8), 256, 0, stream>>>(y, Wt2, bproj, out);
}

// Round 16
// 127.139 us; speedup vs baseline: 1.0935x; 1.0401x over previous
//
#include <hip/hip_runtime.h>
#include <stdint.h>

typedef __attribute__((ext_vector_type(8))) short bf16x8;
typedef __attribute__((ext_vector_type(4))) float f32x4;
typedef __attribute__((ext_vector_type(4))) unsigned short us4;

#define DEV static __device__ __forceinline__

DEV unsigned short f2b(float f){
  union{float f; unsigned u;} x; x.f=f;
  unsigned r = x.u + 0x7fffu + ((x.u>>16)&1u);
  return (unsigned short)(r>>16);
}

DEV void glds16(const void* g, void* l){
  __builtin_amdgcn_global_load_lds((const __attribute__((address_space(1))) void*)g,
                                   (__attribute__((address_space(3))) void*)l, 16, 0, 0);
}

// ---------------- convert: f32 -> bf16 ----------------
__global__ __launch_bounds__(256) void convert_k(const float* __restrict__ in,
                                                 unsigned short* __restrict__ out, int n){
  int i = (blockIdx.x*256 + threadIdx.x)*8;
  if(i >= n) return;
  f32x4 a = *(const f32x4*)(in + i);
  f32x4 b = *(const f32x4*)(in + i + 4);
  us4 o0, o1;
  o0.x=f2b(a[0]); o0.y=f2b(a[1]); o0.z=f2b(a[2]); o0.w=f2b(a[3]);
  o1.x=f2b(b[0]); o1.y=f2b(b[1]); o1.z=f2b(b[2]); o1.w=f2b(b[3]);
  *(us4*)(out + i) = o0;
  *(us4*)(out + i + 4) = o1;
}

// ------- merged transpose+convert: w_qkv (x<48) and w_proj (x>=48) in ONE launch -------
__global__ __launch_bounds__(256) void transpose2_k(const float* __restrict__ in1,
                                                    unsigned short* __restrict__ out1,
                                                    const float* __restrict__ in2,
                                                    unsigned short* __restrict__ out2){
  __shared__ __attribute__((aligned(16))) unsigned short tile[64][72];
  const int bx = blockIdx.x;
  const float* in;  unsigned short* out;  int ldin, ldout, c0;
  if(bx < 48){ in = in1; out = out1; ldin = 3072; ldout = 1024; c0 = bx*64; }
  else       { in = in2; out = out2; ldin = 1024; ldout = 1024; c0 = (bx-48)*64; }
  const int r0 = blockIdx.y*64;
  const int t = threadIdx.x;
  const int tr = t>>4, tc4 = (t&15)*4;
  #pragma unroll
  for(int j=0;j<4;j++){
    int r = tr + j*16;
    f32x4 v = *(const f32x4*)(in + (size_t)(r0+r)*ldin + c0 + tc4);
    tile[r][tc4+0] = f2b(v[0]);
    tile[r][tc4+1] = f2b(v[1]);
    tile[r][tc4+2] = f2b(v[2]);
    tile[r][tc4+3] = f2b(v[3]);
  }
  __syncthreads();
  #pragma unroll
  for(int j=0;j<4;j++){
    int r = tr + j*16;
    us4 v;
    v.x = tile[tc4+0][r];
    v.y = tile[tc4+1][r];
    v.z = tile[tc4+2][r];
    v.w = tile[tc4+3][r];
    *(us4*)(out + (size_t)(c0+r)*ldout + r0 + tc4) = v;
  }
}

// ---------------- shared GEMM core (R11-exact): BK=64, single-buffered ----------------
#define BK 64

DEV void gemm_core_128(const unsigned short* __restrict__ A,
                       const unsigned short* __restrict__ Bt,
                       int K, int rowA0, int rowB0,
                       unsigned short* As, unsigned short* Bs, f32x4 acc[4][4])
{
  const int t = threadIdx.x;
  const int lane = t & 63;
  const int wid  = t >> 6;
  const int wm = wid >> 1, wn = wid & 1;
  const f32x4 Z = {0.f,0.f,0.f,0.f};

  #pragma unroll
  for(int m=0;m<4;m++)
    #pragma unroll
    for(int n=0;n<4;n++) acc[m][n] = Z;

  for(int kt=0; kt<K; kt+=BK){
    __syncthreads();
    #pragma unroll
    for(int j=0;j<4;j++){
      int idx = t + 256*j;          // 16B chunk index, 1024 chunks = 128 rows x 8
      int row = idx >> 3;
      int ls  = (idx & 7) ^ (row & 7);
      glds16(A + (size_t)(rowA0 + row)*K + kt + ls*8, As + (size_t)(wid*64 + 256*j)*8);
    }
    #pragma unroll
    for(int j=0;j<4;j++){
      int idx = t + 256*j;
      int row = idx >> 3;
      int ls  = (idx & 7) ^ (row & 7);
      glds16(Bt + (size_t)(rowB0 + row)*K + kt + ls*8, Bs + (size_t)(wid*64 + 256*j)*8);
    }
    __syncthreads();
    #pragma unroll
    for(int ks=0; ks<2; ks++){
      bf16x8 af[4], bfr[4];
      #pragma unroll
      for(int m=0;m<4;m++){
        int row = wm*64 + m*16 + (lane&15);
        int sl  = (ks*4 + (lane>>4)) ^ (row&7);
        af[m] = *(const bf16x8*)(As + row*64 + sl*8);
      }
      #pragma unroll
      for(int n=0;n<4;n++){
        int row = wn*64 + n*16 + (lane&15);
        int sl  = (ks*4 + (lane>>4)) ^ (row&7);
        bfr[n] = *(const bf16x8*)(Bs + row*64 + sl*8);
      }
      #pragma unroll
      for(int m=0;m<4;m++)
        #pragma unroll
        for(int n=0;n<4;n++)
          acc[m][n] = __builtin_amdgcn_mfma_f32_16x16x32_bf16(af[m], bfr[n], acc[m][n], 0, 0, 0);
    }
  }
}

// ---------------- GEMM1: qkv = xb @ w_qkv + b -> q,k [bh][n][d]; V stored TRANSPOSED ----
__global__ __launch_bounds__(256) void gemm_qkv(const unsigned short* __restrict__ xb,
                                                const unsigned short* __restrict__ Wt,
                                                const float* __restrict__ bqkv,
                                                unsigned short* __restrict__ q,
                                                unsigned short* __restrict__ k,
                                                unsigned short* __restrict__ vt)
{
  __shared__ __attribute__((aligned(16))) unsigned short SMEM[2*128*BK];  // 32KB
  unsigned short* As = SMEM;
  unsigned short* Bs = SMEM + 128*BK;
  f32x4 acc[4][4];
  const int bm = blockIdx.x, bn = blockIdx.y;
  gemm_core_128(xb, Wt, 1024, bm*128, bn*128, As, Bs, acc);
  __syncthreads();   // all waves done reading As/Bs before epilogue reuse

  const int t = threadIdx.x, lane = t&63, wid = t>>6, wm = wid>>1, wn = wid&1;
  const int col0 = bn*128 + wn*64;          // 64-aligned -> one source (q/k/v), one head
  const int three = col0 >> 10;
  const int h = (col0>>6)&15;
  const int row0 = bm*128 + wm*64;          // 64 tokens, within one batch
  const int bb = row0 >> 11, nn0 = row0 & 2047;
  const size_t bh = (size_t)(bb*16 + h);

  if(three < 2){
    unsigned short* dst = (three==0) ? q : k;
    #pragma unroll
    for(int m=0;m<4;m++)
      #pragma unroll
      for(int n=0;n<4;n++){
        int d = (col0 & 63) + n*16 + (lane&15);        // 0..63
        float bias = bqkv[col0 + n*16 + (lane&15)];
        #pragma unroll
        for(int r=0;r<4;r++){
          int nn = nn0 + m*16 + (lane>>4)*4 + r;
          dst[(bh*2048 + nn)*64 + d] = f2b(acc[m][n][r] + bias);
        }
      }
  } else {
    // V: stage wave tile as [d][n] in own LDS region, then coalesced store
    unsigned short* ep = SMEM + wid*4096;   // 64*64 elems = 8KB
    #pragma unroll
    for(int n=0;n<4;n++){
      int dl = n*16 + (lane&15);
      float bias = bqkv[col0 + dl];
      #pragma unroll
      for(int m=0;m<4;m++){
        int nl = m*16 + (lane>>4)*4;
        unsigned w0, w1;
        float a0 = acc[m][n][0] + bias, a1 = acc[m][n][1] + bias;
        float a2 = acc[m][n][2] + bias, a3 = acc[m][n][3] + bias;
        asm("v_cvt_pk_bf16_f32 %0, %1, %2" : "=v"(w0) : "v"(a0), "v"(a1));
        asm("v_cvt_pk_bf16_f32 %0, %1, %2" : "=v"(w1) : "v"(a2), "v"(a3));
        *(unsigned*)(ep + dl*64 + nl)     = w0;
        *(unsigned*)(ep + dl*64 + nl + 2) = w1;
      }
    }
    // same-wave readback (program-order DS within a wave; compiler inserts waits)
    #pragma unroll
    for(int p=0;p<16;p++){
      int dl = p*4 + (lane>>4);
      us4 vv = *(const us4*)(ep + dl*64 + (lane&15)*4);
      *(us4*)(vt + (bh*64 + dl)*2048 + nn0 + (lane&15)*4) = vv;
    }
  }
}

// ---------------- GEMM2 v2: 64x128 tiles, grid (64,8)=512 blocks -> 2 blocks/CU ----
// Same swizzle/staging algebra as gemm_core_128; wave(wm,wn) owns 32x64, acc[2][4].
__global__ __launch_bounds__(256) void gemm_proj(const unsigned short* __restrict__ y,
                                                 const unsigned short* __restrict__ Wt,
                                                 const float* __restrict__ bp,
                                                 float* __restrict__ out)
{
  __shared__ __attribute__((aligned(16))) unsigned short As[64*BK];    // 8KB
  __shared__ __attribute__((aligned(16))) unsigned short Bs[128*BK];   // 16KB
  const int bm = blockIdx.x, bn = blockIdx.y;
  const int t = threadIdx.x, lane = t&63, wid = t>>6;
  const int wm = wid>>1, wn = wid&1;
  const int lq = lane&15, lh = lane>>4;
  const int rowA0 = bm*64, rowB0 = bn*128;
  const f32x4 Z = {0.f,0.f,0.f,0.f};
  f32x4 acc[2][4];
  #pragma unroll
  for(int m=0;m<2;m++)
    #pragma unroll
    for(int n=0;n<4;n++) acc[m][n] = Z;

  for(int kt=0; kt<1024; kt+=BK){
    __syncthreads();
    #pragma unroll
    for(int j=0;j<2;j++){          // A: 512 chunks = 64 rows x 8
      int idx = t + 256*j;
      int row = idx >> 3;
      int ls  = (idx & 7) ^ (row & 7);
      glds16(y + (size_t)(rowA0 + row)*1024 + kt + ls*8, As + (size_t)(wid*64 + 256*j)*8);
    }
    #pragma unroll
    for(int j=0;j<4;j++){          // B: 1024 chunks = 128 rows x 8
      int idx = t + 256*j;
      int row = idx >> 3;
      int ls  = (idx & 7) ^ (row & 7);
      glds16(Wt + (size_t)(rowB0 + row)*1024 + kt + ls*8, Bs + (size_t)(wid*64 + 256*j)*8);
    }
    __syncthreads();
    #pragma unroll
    for(int ks=0; ks<2; ks++){
      bf16x8 af[2], bfr[4];
      #pragma unroll
      for(int m=0;m<2;m++){
        int row = wm*32 + m*16 + lq;
        int sl  = (ks*4 + lh) ^ (row&7);
        af[m] = *(const bf16x8*)(As + row*64 + sl*8);
      }
      #pragma unroll
      for(int n=0;n<4;n++){
        int row = wn*64 + n*16 + lq;
        int sl  = (ks*4 + lh) ^ (row&7);
        bfr[n] = *(const bf16x8*)(Bs + row*64 + sl*8);
      }
      #pragma unroll
      for(int m=0;m<2;m++)
        #pragma unroll
        for(int n=0;n<4;n++)
          acc[m][n] = __builtin_amdgcn_mfma_f32_16x16x32_bf16(af[m], bfr[n], acc[m][n], 0, 0, 0);
    }
  }

  #pragma unroll
  for(int m=0;m<2;m++)
    #pragma unroll
    for(int n=0;n<4;n++){
      int col = bn*128 + wn*64 + n*16 + lq;
      float bias = bp[col];
      #pragma unroll
      for(int r=0;r<4;r++){
        int row = bm*64 + wm*32 + m*16 + lh*4 + r;
        out[(size_t)row*1024 + col] = acc[m][n][r] + bias;
      }
    }
}

// ---------------- flash attention v6 (R13-exact, proven 62us): 64 q-rows/block ----
__global__ __launch_bounds__(256, 4) void attn_k(const unsigned short* __restrict__ qg,
                                                 const unsigned short* __restrict__ kg,
                                                 const unsigned short* __restrict__ vtg,
                                                 unsigned short* __restrict__ y)
{
  __shared__ __attribute__((aligned(16))) unsigned short Ks[2][64*64];  // [kv][d] swizzled
  __shared__ __attribute__((aligned(16))) unsigned short VT[2][64*64];  // [d][kv] swizzled
  __shared__ __attribute__((aligned(16))) unsigned short Ps[4][16*64];  // per-wave P^T, swizzled

  const int bh = blockIdx.x;      // b*16 + h
  const int qt = blockIdx.y;      // 0..31
  const int b  = bh >> 4, h = bh & 15;
  const unsigned short* qh = qg  + (size_t)bh*2048*64;
  const unsigned short* kh = kg  + (size_t)bh*2048*64;
  const unsigned short* vh = vtg + (size_t)bh*64*2048;

  const int t = threadIdx.x, lane = t & 63, wid = t >> 6;
  const int q0 = qt*64 + wid*16;
  const int lq = lane & 15;
  const int lh = lane >> 4;                 // 16-lane group 0..3
  const float C1 = 0.18033688011112042f;    // (1/8) * log2(e)

  // Q fragments (B-operand pattern) held in registers
  bf16x8 aq[2];
  #pragma unroll
  for(int ks=0;ks<2;ks++){
    int row = q0 + lq;
    aq[ks] = *(const bf16x8*)(qh + (size_t)row*64 + ks*32 + lh*8);
  }

  const f32x4 Z = {0.f,0.f,0.f,0.f};
  f32x4 accT[4];                    // O^T tiles per d-subtile
  #pragma unroll
  for(int df=0;df<4;df++) accT[df] = Z;
  float lpart = 0.f;                // per-lane partial row-sum

  // prologue: stage tile 0 into buffer 0
  #pragma unroll
  for(int j=0;j<2;j++){
    int idx = t + 256*j;
    int row = idx >> 3;
    int ls  = (idx & 7) ^ (row & 7);
    glds16(kh + (size_t)row*64 + ls*8, &Ks[0][0] + (wid*64 + 256*j)*8);
    glds16(vh + (size_t)row*2048 + ls*8, &VT[0][0] + (wid*64 + 256*j)*8);
  }
  __syncthreads();

  for(int it=0; it<32; ++it){
    const int cur = it & 1, nxt = cur ^ 1;
    // prefetch next tile (loads stay in flight across the compute phase)
    if(it < 31){
      int kvn = (it+1)*64;
      #pragma unroll
      for(int j=0;j<2;j++){
        int idx = t + 256*j;
        int row = idx >> 3;
        int ls  = (idx & 7) ^ (row & 7);
        glds16(kh + (size_t)(kvn+row)*64 + ls*8, &Ks[nxt][0] + (wid*64 + 256*j)*8);
        glds16(vh + (size_t)row*2048 + kvn + ls*8, &VT[nxt][0] + (wid*64 + 256*j)*8);
      }
    }

    // S^T = mfma(K, Q)
    f32x4 st[4];
    #pragma unroll
    for(int nc=0;nc<4;nc++) st[nc] = Z;
    __builtin_amdgcn_s_setprio(1);
    #pragma unroll
    for(int ks=0;ks<2;ks++){
      bf16x8 bk[4];
      #pragma unroll
      for(int nc=0;nc<4;nc++){
        int kvr = nc*16 + lq;
        int sl  = (ks*4 + lh) ^ (kvr&7);
        bk[nc] = *(const bf16x8*)(&Ks[cur][0] + kvr*64 + sl*8);
      }
      #pragma unroll
      for(int nc=0;nc<4;nc++)
        st[nc] = __builtin_amdgcn_mfma_f32_16x16x32_bf16(bk[nc], aq[ks], st[nc], 0,0,0);
    }
    __builtin_amdgcn_s_setprio(0);

    // softmax numerator p = 2^(s*C1): raw v_exp + cvt_pk pack + swizzled 8B LDS write
    {
      float rs = 0.f;
      unsigned short* pr = &Ps[wid][0] + lq*64;   // 128B row
      #pragma unroll
      for(int nc=0;nc<4;nc++){
        float p0 = __builtin_amdgcn_exp2f(st[nc][0]*C1);
        float p1 = __builtin_amdgcn_exp2f(st[nc][1]*C1);
        float p2 = __builtin_amdgcn_exp2f(st[nc][2]*C1);
        float p3 = __builtin_amdgcn_exp2f(st[nc][3]*C1);
        rs += (p0+p1)+(p2+p3);
        unsigned w0, w1;
        asm("v_cvt_pk_bf16_f32 %0, %1, %2" : "=v"(w0) : "v"(p0), "v"(p1));
        asm("v_cvt_pk_bf16_f32 %0, %1, %2" : "=v"(w1) : "v"(p2), "v"(p3));
        int g    = 2*nc + (lh>>1);
        int phys = g ^ (lane&7);
        unsigned* dst = (unsigned*)(pr + phys*8 + (lh&1)*4);
        dst[0] = w0; dst[1] = w1;
      }
      lpart += rs;
    }

    // O^T += mfma(V^T, P^T)  (own-wave Ps region; same-wave DS ordering)
    __builtin_amdgcn_s_setprio(1);
    #pragma unroll
    for(int ks=0;ks<2;ks++){
      bf16x8 bv[4], pa;
      #pragma unroll
      for(int df=0;df<4;df++){
        int dr = df*16 + lq;
        int sl = (ks*4 + lh) ^ (dr&7);
        bv[df] = *(const bf16x8*)(&VT[cur][0] + dr*64 + sl*8);
      }
      {
        int g    = 4*ks + lh;
        int phys = g ^ (lane&7);
        pa = *(const bf16x8*)(&Ps[wid][0] + lq*64 + phys*8);
      }
      #pragma unroll
      for(int df=0;df<4;df++)
        accT[df] = __builtin_amdgcn_mfma_f32_16x16x32_bf16(bv[df], pa, accT[df], 0,0,0);
    }
    __builtin_amdgcn_s_setprio(0);

    __syncthreads();   // drains this wave's prefetch glds + all waves' LDS reads of cur
  }

  // epilogue: one cross-lane sum, then normalize + store
  float ls = lpart;
  ls += __shfl_xor(ls, 16, 64);
  ls += __shfl_xor(ls, 32, 64);
  float rl = 1.0f / ls;
  int row = q0 + lq;
  #pragma unroll
  for(int df=0;df<4;df++){
    us4 o;
    o.x = f2b(accT[df][0] * rl);
    o.y = f2b(accT[df][1] * rl);
    o.z = f2b(accT[df][2] * rl);
    o.w = f2b(accT[df][3] * rl);
    *(us4*)(y + ((size_t)b*2048 + row)*1024 + h*64 + df*16 + lh*4) = o;
  }
}

extern "C" void kernel_launch(void* const* d_in, const int* in_sizes, int n_in,
                              void* d_out, int out_size, void* d_ws, size_t ws_size,
                              hipStream_t stream) {
  const float* x     = (const float*)d_in[0];
  const float* wqkv  = (const float*)d_in[1];
  const float* bqkv  = (const float*)d_in[2];
  const float* wproj = (const float*)d_in[3];
  const float* bproj = (const float*)d_in[4];
  float* out = (float*)d_out;

  char* ws = (char*)d_ws;
  unsigned short* Wt1 = (unsigned short*)ws;  ws += (size_t)3072*1024*2;
  unsigned short* Wt2 = (unsigned short*)ws;  ws += (size_t)1024*1024*2;
  unsigned short* xb  = (unsigned short*)ws;  ws += (size_t)2*2048*1024*2;
  unsigned short* q   = (unsigned short*)ws;  ws += (size_t)2*16*2048*64*2;
  unsigned short* k   = (unsigned short*)ws;  ws += (size_t)2*16*2048*64*2;
  unsigned short* vt  = (unsigned short*)ws;  ws += (size_t)2*16*2048*64*2;
  unsigned short* y   = (unsigned short*)ws;  ws += (size_t)2*2048*1024*2;

  convert_k   <<<2048, 256, 0, stream>>>(x, xb, 2*2048*1024);
  transpose2_k<<<dim3(64,16), 256, 0, stream>>>(wqkv, Wt1, wproj, Wt2);
  gemm_qkv   <<<dim3(32,24), 256, 0, stream>>>(xb, Wt1, bqkv, q, k, vt);
  attn_k     <<<dim3(32,32), 256, 0, stream>>>(q, k, vt, y);
  gemm_proj  <<<dim3(64, 8), 256, 0, stream>>>(y, Wt2, bproj, out);
}

// Round 17
// 127.047 us; speedup vs baseline: 1.0943x; 1.0007x over previous
//
#include <hip/hip_runtime.h>
#include <stdint.h>

typedef __attribute__((ext_vector_type(8))) short bf16x8;
typedef __attribute__((ext_vector_type(4))) float f32x4;
typedef __attribute__((ext_vector_type(4))) unsigned short us4;

#define DEV static __device__ __forceinline__

DEV unsigned short f2b(float f){
  union{float f; unsigned u;} x; x.f=f;
  unsigned r = x.u + 0x7fffu + ((x.u>>16)&1u);
  return (unsigned short)(r>>16);
}

DEV void glds16(const void* g, void* l){
  __builtin_amdgcn_global_load_lds((const __attribute__((address_space(1))) void*)g,
                                   (__attribute__((address_space(3))) void*)l, 16, 0, 0);
}

// ---------------- convert: f32 -> bf16 ----------------
__global__ __launch_bounds__(256) void convert_k(const float* __restrict__ in,
                                                 unsigned short* __restrict__ out, int n){
  int i = (blockIdx.x*256 + threadIdx.x)*8;
  if(i >= n) return;
  f32x4 a = *(const f32x4*)(in + i);
  f32x4 b = *(const f32x4*)(in + i + 4);
  us4 o0, o1;
  o0.x=f2b(a[0]); o0.y=f2b(a[1]); o0.z=f2b(a[2]); o0.w=f2b(a[3]);
  o1.x=f2b(b[0]); o1.y=f2b(b[1]); o1.z=f2b(b[2]); o1.w=f2b(b[3]);
  *(us4*)(out + i) = o0;
  *(us4*)(out + i + 4) = o1;
}

// ------- merged transpose+convert: w_qkv (x<48) and w_proj (x>=48) in ONE launch -------
__global__ __launch_bounds__(256) void transpose2_k(const float* __restrict__ in1,
                                                    unsigned short* __restrict__ out1,
                                                    const float* __restrict__ in2,
                                                    unsigned short* __restrict__ out2){
  __shared__ __attribute__((aligned(16))) unsigned short tile[64][72];
  const int bx = blockIdx.x;
  const float* in;  unsigned short* out;  int ldin, ldout, c0;
  if(bx < 48){ in = in1; out = out1; ldin = 3072; ldout = 1024; c0 = bx*64; }
  else       { in = in2; out = out2; ldin = 1024; ldout = 1024; c0 = (bx-48)*64; }
  const int r0 = blockIdx.y*64;
  const int t = threadIdx.x;
  const int tr = t>>4, tc4 = (t&15)*4;
  #pragma unroll
  for(int j=0;j<4;j++){
    int r = tr + j*16;
    f32x4 v = *(const f32x4*)(in + (size_t)(r0+r)*ldin + c0 + tc4);
    tile[r][tc4+0] = f2b(v[0]);
    tile[r][tc4+1] = f2b(v[1]);
    tile[r][tc4+2] = f2b(v[2]);
    tile[r][tc4+3] = f2b(v[3]);
  }
  __syncthreads();
  #pragma unroll
  for(int j=0;j<4;j++){
    int r = tr + j*16;
    us4 v;
    v.x = tile[tc4+0][r];
    v.y = tile[tc4+1][r];
    v.z = tile[tc4+2][r];
    v.w = tile[tc4+3][r];
    *(us4*)(out + (size_t)(c0+r)*ldout + r0 + tc4) = v;
  }
}

// ---------------- shared GEMM core (R11-exact): BK=64, single-buffered ----------------
#define BK 64

DEV void gemm_core_128(const unsigned short* __restrict__ A,
                       const unsigned short* __restrict__ Bt,
                       int K, int rowA0, int rowB0,
                       unsigned short* As, unsigned short* Bs, f32x4 acc[4][4])
{
  const int t = threadIdx.x;
  const int lane = t & 63;
  const int wid  = t >> 6;
  const int wm = wid >> 1, wn = wid & 1;
  const f32x4 Z = {0.f,0.f,0.f,0.f};

  #pragma unroll
  for(int m=0;m<4;m++)
    #pragma unroll
    for(int n=0;n<4;n++) acc[m][n] = Z;

  for(int kt=0; kt<K; kt+=BK){
    __syncthreads();
    #pragma unroll
    for(int j=0;j<4;j++){
      int idx = t + 256*j;          // 16B chunk index, 1024 chunks = 128 rows x 8
      int row = idx >> 3;
      int ls  = (idx & 7) ^ (row & 7);
      glds16(A + (size_t)(rowA0 + row)*K + kt + ls*8, As + (size_t)(wid*64 + 256*j)*8);
    }
    #pragma unroll
    for(int j=0;j<4;j++){
      int idx = t + 256*j;
      int row = idx >> 3;
      int ls  = (idx & 7) ^ (row & 7);
      glds16(Bt + (size_t)(rowB0 + row)*K + kt + ls*8, Bs + (size_t)(wid*64 + 256*j)*8);
    }
    __syncthreads();
    #pragma unroll
    for(int ks=0; ks<2; ks++){
      bf16x8 af[4], bfr[4];
      #pragma unroll
      for(int m=0;m<4;m++){
        int row = wm*64 + m*16 + (lane&15);
        int sl  = (ks*4 + (lane>>4)) ^ (row&7);
        af[m] = *(const bf16x8*)(As + row*64 + sl*8);
      }
      #pragma unroll
      for(int n=0;n<4;n++){
        int row = wn*64 + n*16 + (lane&15);
        int sl  = (ks*4 + (lane>>4)) ^ (row&7);
        bfr[n] = *(const bf16x8*)(Bs + row*64 + sl*8);
      }
      #pragma unroll
      for(int m=0;m<4;m++)
        #pragma unroll
        for(int n=0;n<4;n++)
          acc[m][n] = __builtin_amdgcn_mfma_f32_16x16x32_bf16(af[m], bfr[n], acc[m][n], 0, 0, 0);
    }
  }
}

// ---------------- GEMM1: qkv = xb @ w_qkv + b -> q,k [bh][n][d]; V stored TRANSPOSED ----
__global__ __launch_bounds__(256) void gemm_qkv(const unsigned short* __restrict__ xb,
                                                const unsigned short* __restrict__ Wt,
                                                const float* __restrict__ bqkv,
                                                unsigned short* __restrict__ q,
                                                unsigned short* __restrict__ k,
                                                unsigned short* __restrict__ vt)
{
  __shared__ __attribute__((aligned(16))) unsigned short SMEM[2*128*BK];  // 32KB
  unsigned short* As = SMEM;
  unsigned short* Bs = SMEM + 128*BK;
  f32x4 acc[4][4];
  const int bm = blockIdx.x, bn = blockIdx.y;
  gemm_core_128(xb, Wt, 1024, bm*128, bn*128, As, Bs, acc);
  __syncthreads();   // all waves done reading As/Bs before epilogue reuse

  const int t = threadIdx.x, lane = t&63, wid = t>>6, wm = wid>>1, wn = wid&1;
  const int col0 = bn*128 + wn*64;          // 64-aligned -> one source (q/k/v), one head
  const int three = col0 >> 10;
  const int h = (col0>>6)&15;
  const int row0 = bm*128 + wm*64;          // 64 tokens, within one batch
  const int bb = row0 >> 11, nn0 = row0 & 2047;
  const size_t bh = (size_t)(bb*16 + h);

  if(three < 2){
    unsigned short* dst = (three==0) ? q : k;
    #pragma unroll
    for(int m=0;m<4;m++)
      #pragma unroll
      for(int n=0;n<4;n++){
        int d = (col0 & 63) + n*16 + (lane&15);        // 0..63
        float bias = bqkv[col0 + n*16 + (lane&15)];
        #pragma unroll
        for(int r=0;r<4;r++){
          int nn = nn0 + m*16 + (lane>>4)*4 + r;
          dst[(bh*2048 + nn)*64 + d] = f2b(acc[m][n][r] + bias);
        }
      }
  } else {
    // V: stage wave tile as [d][n] in own LDS region, then coalesced store
    unsigned short* ep = SMEM + wid*4096;   // 64*64 elems = 8KB
    #pragma unroll
    for(int n=0;n<4;n++){
      int dl = n*16 + (lane&15);
      float bias = bqkv[col0 + dl];
      #pragma unroll
      for(int m=0;m<4;m++){
        int nl = m*16 + (lane>>4)*4;
        unsigned w0, w1;
        float a0 = acc[m][n][0] + bias, a1 = acc[m][n][1] + bias;
        float a2 = acc[m][n][2] + bias, a3 = acc[m][n][3] + bias;
        asm("v_cvt_pk_bf16_f32 %0, %1, %2" : "=v"(w0) : "v"(a0), "v"(a1));
        asm("v_cvt_pk_bf16_f32 %0, %1, %2" : "=v"(w1) : "v"(a2), "v"(a3));
        *(unsigned*)(ep + dl*64 + nl)     = w0;
        *(unsigned*)(ep + dl*64 + nl + 2) = w1;
      }
    }
    // same-wave readback (program-order DS within a wave; compiler inserts waits)
    #pragma unroll
    for(int p=0;p<16;p++){
      int dl = p*4 + (lane>>4);
      us4 vv = *(const us4*)(ep + dl*64 + (lane&15)*4);
      *(us4*)(vt + (bh*64 + dl)*2048 + nn0 + (lane&15)*4) = vv;
    }
  }
}

// ---------------- GEMM2 v2: 64x128 tiles, grid (64,8)=512 blocks -> 2 blocks/CU ----
// Same swizzle/staging algebra as gemm_core_128; wave(wm,wn) owns 32x64, acc[2][4].
__global__ __launch_bounds__(256) void gemm_proj(const unsigned short* __restrict__ y,
                                                 const unsigned short* __restrict__ Wt,
                                                 const float* __restrict__ bp,
                                                 float* __restrict__ out)
{
  __shared__ __attribute__((aligned(16))) unsigned short As[64*BK];    // 8KB
  __shared__ __attribute__((aligned(16))) unsigned short Bs[128*BK];   // 16KB
  const int bm = blockIdx.x, bn = blockIdx.y;
  const int t = threadIdx.x, lane = t&63, wid = t>>6;
  const int wm = wid>>1, wn = wid&1;
  const int lq = lane&15, lh = lane>>4;
  const int rowA0 = bm*64, rowB0 = bn*128;
  const f32x4 Z = {0.f,0.f,0.f,0.f};
  f32x4 acc[2][4];
  #pragma unroll
  for(int m=0;m<2;m++)
    #pragma unroll
    for(int n=0;n<4;n++) acc[m][n] = Z;

  for(int kt=0; kt<1024; kt+=BK){
    __syncthreads();
    #pragma unroll
    for(int j=0;j<2;j++){          // A: 512 chunks = 64 rows x 8
      int idx = t + 256*j;
      int row = idx >> 3;
      int ls  = (idx & 7) ^ (row & 7);
      glds16(y + (size_t)(rowA0 + row)*1024 + kt + ls*8, As + (size_t)(wid*64 + 256*j)*8);
    }
    #pragma unroll
    for(int j=0;j<4;j++){          // B: 1024 chunks = 128 rows x 8
      int idx = t + 256*j;
      int row = idx >> 3;
      int ls  = (idx & 7) ^ (row & 7);
      glds16(Wt + (size_t)(rowB0 + row)*1024 + kt + ls*8, Bs + (size_t)(wid*64 + 256*j)*8);
    }
    __syncthreads();
    #pragma unroll
    for(int ks=0; ks<2; ks++){
      bf16x8 af[2], bfr[4];
      #pragma unroll
      for(int m=0;m<2;m++){
        int row = wm*32 + m*16 + lq;
        int sl  = (ks*4 + lh) ^ (row&7);
        af[m] = *(const bf16x8*)(As + row*64 + sl*8);
      }
      #pragma unroll
      for(int n=0;n<4;n++){
        int row = wn*64 + n*16 + lq;
        int sl  = (ks*4 + lh) ^ (row&7);
        bfr[n] = *(const bf16x8*)(Bs + row*64 + sl*8);
      }
      #pragma unroll
      for(int m=0;m<2;m++)
        #pragma unroll
        for(int n=0;n<4;n++)
          acc[m][n] = __builtin_amdgcn_mfma_f32_16x16x32_bf16(af[m], bfr[n], acc[m][n], 0, 0, 0);
    }
  }

  #pragma unroll
  for(int m=0;m<2;m++)
    #pragma unroll
    for(int n=0;n<4;n++){
      int col = bn*128 + wn*64 + n*16 + lq;
      float bias = bp[col];
      #pragma unroll
      for(int r=0;r<4;r++){
        int row = bm*64 + wm*32 + m*16 + lh*4 + r;
        out[(size_t)row*1024 + col] = acc[m][n][r] + bias;
      }
    }
}

// ---------------- flash attention v6 (R13-exact, proven 62us): 64 q-rows/block ----
__global__ __launch_bounds__(256, 4) void attn_k(const unsigned short* __restrict__ qg,
                                                 const unsigned short* __restrict__ kg,
                                                 const unsigned short* __restrict__ vtg,
                                                 unsigned short* __restrict__ y)
{
  __shared__ __attribute__((aligned(16))) unsigned short Ks[2][64*64];  // [kv][d] swizzled
  __shared__ __attribute__((aligned(16))) unsigned short VT[2][64*64];  // [d][kv] swizzled
  __shared__ __attribute__((aligned(16))) unsigned short Ps[4][16*64];  // per-wave P^T, swizzled

  const int bh = blockIdx.x;      // b*16 + h
  const int qt = blockIdx.y;      // 0..31
  const int b  = bh >> 4, h = bh & 15;
  const unsigned short* qh = qg  + (size_t)bh*2048*64;
  const unsigned short* kh = kg  + (size_t)bh*2048*64;
  const unsigned short* vh = vtg + (size_t)bh*64*2048;

  const int t = threadIdx.x, lane = t & 63, wid = t >> 6;
  const int q0 = qt*64 + wid*16;
  const int lq = lane & 15;
  const int lh = lane >> 4;                 // 16-lane group 0..3
  const float C1 = 0.18033688011112042f;    // (1/8) * log2(e)

  // Q fragments (B-operand pattern) held in registers
  bf16x8 aq[2];
  #pragma unroll
  for(int ks=0;ks<2;ks++){
    int row = q0 + lq;
    aq[ks] = *(const bf16x8*)(qh + (size_t)row*64 + ks*32 + lh*8);
  }

  const f32x4 Z = {0.f,0.f,0.f,0.f};
  f32x4 accT[4];                    // O^T tiles per d-subtile
  #pragma unroll
  for(int df=0;df<4;df++) accT[df] = Z;
  float lpart = 0.f;                // per-lane partial row-sum

  // prologue: stage tile 0 into buffer 0
  #pragma unroll
  for(int j=0;j<2;j++){
    int idx = t + 256*j;
    int row = idx >> 3;
    int ls  = (idx & 7) ^ (row & 7);
    glds16(kh + (size_t)row*64 + ls*8, &Ks[0][0] + (wid*64 + 256*j)*8);
    glds16(vh + (size_t)row*2048 + ls*8, &VT[0][0] + (wid*64 + 256*j)*8);
  }
  __syncthreads();

  for(int it=0; it<32; ++it){
    const int cur = it & 1, nxt = cur ^ 1;
    // prefetch next tile (loads stay in flight across the compute phase)
    if(it < 31){
      int kvn = (it+1)*64;
      #pragma unroll
      for(int j=0;j<2;j++){
        int idx = t + 256*j;
        int row = idx >> 3;
        int ls  = (idx & 7) ^ (row & 7);
        glds16(kh + (size_t)(kvn+row)*64 + ls*8, &Ks[nxt][0] + (wid*64 + 256*j)*8);
        glds16(vh + (size_t)row*2048 + kvn + ls*8, &VT[nxt][0] + (wid*64 + 256*j)*8);
      }
    }

    // S^T = mfma(K, Q)
    f32x4 st[4];
    #pragma unroll
    for(int nc=0;nc<4;nc++) st[nc] = Z;
    __builtin_amdgcn_s_setprio(1);
    #pragma unroll
    for(int ks=0;ks<2;ks++){
      bf16x8 bk[4];
      #pragma unroll
      for(int nc=0;nc<4;nc++){
        int kvr = nc*16 + lq;
        int sl  = (ks*4 + lh) ^ (kvr&7);
        bk[nc] = *(const bf16x8*)(&Ks[cur][0] + kvr*64 + sl*8);
      }
      #pragma unroll
      for(int nc=0;nc<4;nc++)
        st[nc] = __builtin_amdgcn_mfma_f32_16x16x32_bf16(bk[nc], aq[ks], st[nc], 0,0,0);
    }
    __builtin_amdgcn_s_setprio(0);

    // softmax numerator p = 2^(s*C1): raw v_exp + cvt_pk pack + swizzled 8B LDS write
    {
      float rs = 0.f;
      unsigned short* pr = &Ps[wid][0] + lq*64;   // 128B row
      #pragma unroll
      for(int nc=0;nc<4;nc++){
        float p0 = __builtin_amdgcn_exp2f(st[nc][0]*C1);
        float p1 = __builtin_amdgcn_exp2f(st[nc][1]*C1);
        float p2 = __builtin_amdgcn_exp2f(st[nc][2]*C1);
        float p3 = __builtin_amdgcn_exp2f(st[nc][3]*C1);
        rs += (p0+p1)+(p2+p3);
        unsigned w0, w1;
        asm("v_cvt_pk_bf16_f32 %0, %1, %2" : "=v"(w0) : "v"(p0), "v"(p1));
        asm("v_cvt_pk_bf16_f32 %0, %1, %2" : "=v"(w1) : "v"(p2), "v"(p3));
        int g    = 2*nc + (lh>>1);
        int phys = g ^ (lane&7);
        unsigned* dst = (unsigned*)(pr + phys*8 + (lh&1)*4);
        dst[0] = w0; dst[1] = w1;
      }
      lpart += rs;
    }

    // O^T += mfma(V^T, P^T)  (own-wave Ps region; same-wave DS ordering)
    __builtin_amdgcn_s_setprio(1);
    #pragma unroll
    for(int ks=0;ks<2;ks++){
      bf16x8 bv[4], pa;
      #pragma unroll
      for(int df=0;df<4;df++){
        int dr = df*16 + lq;
        int sl = (ks*4 + lh) ^ (dr&7);
        bv[df] = *(const bf16x8*)(&VT[cur][0] + dr*64 + sl*8);
      }
      {
        int g    = 4*ks + lh;
        int phys = g ^ (lane&7);
        pa = *(const bf16x8*)(&Ps[wid][0] + lq*64 + phys*8);
      }
      #pragma unroll
      for(int df=0;df<4;df++)
        accT[df] = __builtin_amdgcn_mfma_f32_16x16x32_bf16(bv[df], pa, accT[df], 0,0,0);
    }
    __builtin_amdgcn_s_setprio(0);

    __syncthreads();   // drains this wave's prefetch glds + all waves' LDS reads of cur
  }

  // epilogue: one cross-lane sum, then normalize + store
  float ls = lpart;
  ls += __shfl_xor(ls, 16, 64);
  ls += __shfl_xor(ls, 32, 64);
  float rl = 1.0f / ls;
  int row = q0 + lq;
  #pragma unroll
  for(int df=0;df<4;df++){
    us4 o;
    o.x = f2b(accT[df][0] * rl);
    o.y = f2b(accT[df][1] * rl);
    o.z = f2b(accT[df][2] * rl);
    o.w = f2b(accT[df][3] * rl);
    *(us4*)(y + ((size_t)b*2048 + row)*1024 + h*64 + df*16 + lh*4) = o;
  }
}

extern "C" void kernel_launch(void* const* d_in, const int* in_sizes, int n_in,
                              void* d_out, int out_size, void* d_ws, size_t ws_size,
                              hipStream_t stream) {
  const float* x     = (const float*)d_in[0];
  const float* wqkv  = (const float*)d_in[1];
  const float* bqkv  = (const float*)d_in[2];
  const float* wproj = (const float*)d_in[3];
  const float* bproj = (const float*)d_in[4];
  float* out = (float*)d_out;

  char* ws = (char*)d_ws;
  unsigned short* Wt1 = (unsigned short*)ws;  ws += (size_t)3072*1024*2;
  unsigned short* Wt2 = (unsigned short*)ws;  ws += (size_t)1024*1024*2;
  unsigned short* xb  = (unsigned short*)ws;  ws += (size_t)2*2048*1024*2;
  unsigned short* q   = (unsigned short*)ws;  ws += (size_t)2*16*2048*64*2;
  unsigned short* k   = (unsigned short*)ws;  ws += (size_t)2*16*2048*64*2;
  unsigned short* vt  = (unsigned short*)ws;  ws += (size_t)2*16*2048*64*2;
  unsigned short* y   = (unsigned short*)ws;  ws += (size_t)2*2048*1024*2;

  convert_k   <<<2048, 256, 0, stream>>>(x, xb, 2*2048*1024);
  transpose2_k<<<dim3(64,16), 256, 0, stream>>>(wqkv, Wt1, wproj, Wt2);
  gemm_qkv   <<<dim3(32,24), 256, 0, stream>>>(xb, Wt1, bqkv, q, k, vt);
  attn_k     <<<dim3(32,32), 256, 0, stream>>>(q, k, vt, y);
  gemm_proj  <<<dim3(64, 8), 256, 0, stream>>>(y, Wt2, bproj, out);
}

// Round 18
// 125.400 us; speedup vs baseline: 1.1087x; 1.0131x over previous
//
#include <hip/hip_runtime.h>
#include <stdint.h>

typedef __attribute__((ext_vector_type(8))) short bf16x8;
typedef __attribute__((ext_vector_type(4))) float f32x4;
typedef __attribute__((ext_vector_type(4))) unsigned short us4;

#define DEV static __device__ __forceinline__

DEV unsigned short f2b(float f){
  union{float f; unsigned u;} x; x.f=f;
  unsigned r = x.u + 0x7fffu + ((x.u>>16)&1u);
  return (unsigned short)(r>>16);
}

DEV void glds16(const void* g, void* l){
  __builtin_amdgcn_global_load_lds((const __attribute__((address_space(1))) void*)g,
                                   (__attribute__((address_space(3))) void*)l, 16, 0, 0);
}

// ---------------- prep: x f32->bf16 convert (bid<2048) + both weight transposes ----------------
__global__ __launch_bounds__(256) void prep_k(const float* __restrict__ x,
                                              unsigned short* __restrict__ xb,
                                              const float* __restrict__ w1,
                                              unsigned short* __restrict__ Wt1,
                                              const float* __restrict__ w2,
                                              unsigned short* __restrict__ Wt2){
  __shared__ __attribute__((aligned(16))) unsigned short tile[64][72];
  const int bid = blockIdx.x;
  const int t = threadIdx.x;

  if(bid < 2048){   // convert: block-uniform branch (no divergent barrier)
    int i = (bid*256 + t)*8;
    f32x4 a = *(const f32x4*)(x + i);
    f32x4 b = *(const f32x4*)(x + i + 4);
    us4 o0, o1;
    o0.x=f2b(a[0]); o0.y=f2b(a[1]); o0.z=f2b(a[2]); o0.w=f2b(a[3]);
    o1.x=f2b(b[0]); o1.y=f2b(b[1]); o1.z=f2b(b[2]); o1.w=f2b(b[3]);
    *(us4*)(xb + i) = o0;
    *(us4*)(xb + i + 4) = o1;
    return;
  }

  const int tb = bid - 2048;          // 0..1023
  const int bx = tb & 63, by = tb >> 6;
  const float* in;  unsigned short* out;  int ldin, c0;
  if(bx < 48){ in = w1; out = Wt1; ldin = 3072; c0 = bx*64; }
  else       { in = w2; out = Wt2; ldin = 1024; c0 = (bx-48)*64; }
  const int ldout = 1024;
  const int r0 = by*64;
  const int tr = t>>4, tc4 = (t&15)*4;
  #pragma unroll
  for(int j=0;j<4;j++){
    int r = tr + j*16;
    f32x4 v = *(const f32x4*)(in + (size_t)(r0+r)*ldin + c0 + tc4);
    tile[r][tc4+0] = f2b(v[0]);
    tile[r][tc4+1] = f2b(v[1]);
    tile[r][tc4+2] = f2b(v[2]);
    tile[r][tc4+3] = f2b(v[3]);
  }
  __syncthreads();
  #pragma unroll
  for(int j=0;j<4;j++){
    int r = tr + j*16;
    us4 v;
    v.x = tile[tc4+0][r];
    v.y = tile[tc4+1][r];
    v.z = tile[tc4+2][r];
    v.w = tile[tc4+3][r];
    *(us4*)(out + (size_t)(c0+r)*ldout + r0 + tc4) = v;
  }
}

// ---------------- shared GEMM core (R11-exact): BK=64, single-buffered ----------------
#define BK 64

DEV void gemm_core_128(const unsigned short* __restrict__ A,
                       const unsigned short* __restrict__ Bt,
                       int K, int rowA0, int rowB0,
                       unsigned short* As, unsigned short* Bs, f32x4 acc[4][4])
{
  const int t = threadIdx.x;
  const int lane = t & 63;
  const int wid  = t >> 6;
  const int wm = wid >> 1, wn = wid & 1;
  const f32x4 Z = {0.f,0.f,0.f,0.f};

  #pragma unroll
  for(int m=0;m<4;m++)
    #pragma unroll
    for(int n=0;n<4;n++) acc[m][n] = Z;

  for(int kt=0; kt<K; kt+=BK){
    __syncthreads();
    #pragma unroll
    for(int j=0;j<4;j++){
      int idx = t + 256*j;          // 16B chunk index, 1024 chunks = 128 rows x 8
      int row = idx >> 3;
      int ls  = (idx & 7) ^ (row & 7);
      glds16(A + (size_t)(rowA0 + row)*K + kt + ls*8, As + (size_t)(wid*64 + 256*j)*8);
    }
    #pragma unroll
    for(int j=0;j<4;j++){
      int idx = t + 256*j;
      int row = idx >> 3;
      int ls  = (idx & 7) ^ (row & 7);
      glds16(Bt + (size_t)(rowB0 + row)*K + kt + ls*8, Bs + (size_t)(wid*64 + 256*j)*8);
    }
    __syncthreads();
    #pragma unroll
    for(int ks=0; ks<2; ks++){
      bf16x8 af[4], bfr[4];
      #pragma unroll
      for(int m=0;m<4;m++){
        int row = wm*64 + m*16 + (lane&15);
        int sl  = (ks*4 + (lane>>4)) ^ (row&7);
        af[m] = *(const bf16x8*)(As + row*64 + sl*8);
      }
      #pragma unroll
      for(int n=0;n<4;n++){
        int row = wn*64 + n*16 + (lane&15);
        int sl  = (ks*4 + (lane>>4)) ^ (row&7);
        bfr[n] = *(const bf16x8*)(Bs + row*64 + sl*8);
      }
      #pragma unroll
      for(int m=0;m<4;m++)
        #pragma unroll
        for(int n=0;n<4;n++)
          acc[m][n] = __builtin_amdgcn_mfma_f32_16x16x32_bf16(af[m], bfr[n], acc[m][n], 0, 0, 0);
    }
  }
}

// ---------------- GEMM1: qkv = xb @ w_qkv + b -> q,k [bh][n][d]; V stored TRANSPOSED ----
__global__ __launch_bounds__(256) void gemm_qkv(const unsigned short* __restrict__ xb,
                                                const unsigned short* __restrict__ Wt,
                                                const float* __restrict__ bqkv,
                                                unsigned short* __restrict__ q,
                                                unsigned short* __restrict__ k,
                                                unsigned short* __restrict__ vt)
{
  __shared__ __attribute__((aligned(16))) unsigned short SMEM[2*128*BK];  // 32KB
  unsigned short* As = SMEM;
  unsigned short* Bs = SMEM + 128*BK;
  f32x4 acc[4][4];
  const int bm = blockIdx.x, bn = blockIdx.y;
  gemm_core_128(xb, Wt, 1024, bm*128, bn*128, As, Bs, acc);
  __syncthreads();   // all waves done reading As/Bs before epilogue reuse

  const int t = threadIdx.x, lane = t&63, wid = t>>6, wm = wid>>1, wn = wid&1;
  const int col0 = bn*128 + wn*64;          // 64-aligned -> one source (q/k/v), one head
  const int three = col0 >> 10;
  const int h = (col0>>6)&15;
  const int row0 = bm*128 + wm*64;          // 64 tokens, within one batch
  const int bb = row0 >> 11, nn0 = row0 & 2047;
  const size_t bh = (size_t)(bb*16 + h);

  if(three < 2){
    unsigned short* dst = (three==0) ? q : k;
    #pragma unroll
    for(int m=0;m<4;m++)
      #pragma unroll
      for(int n=0;n<4;n++){
        int d = (col0 & 63) + n*16 + (lane&15);        // 0..63
        float bias = bqkv[col0 + n*16 + (lane&15)];
        #pragma unroll
        for(int r=0;r<4;r++){
          int nn = nn0 + m*16 + (lane>>4)*4 + r;
          dst[(bh*2048 + nn)*64 + d] = f2b(acc[m][n][r] + bias);
        }
      }
  } else {
    // V: stage wave tile as [d][n] in own LDS region, then coalesced store
    unsigned short* ep = SMEM + wid*4096;   // 64*64 elems = 8KB
    #pragma unroll
    for(int n=0;n<4;n++){
      int dl = n*16 + (lane&15);
      float bias = bqkv[col0 + dl];
      #pragma unroll
      for(int m=0;m<4;m++){
        int nl = m*16 + (lane>>4)*4;
        unsigned w0, w1;
        float a0 = acc[m][n][0] + bias, a1 = acc[m][n][1] + bias;
        float a2 = acc[m][n][2] + bias, a3 = acc[m][n][3] + bias;
        asm("v_cvt_pk_bf16_f32 %0, %1, %2" : "=v"(w0) : "v"(a0), "v"(a1));
        asm("v_cvt_pk_bf16_f32 %0, %1, %2" : "=v"(w1) : "v"(a2), "v"(a3));
        *(unsigned*)(ep + dl*64 + nl)     = w0;
        *(unsigned*)(ep + dl*64 + nl + 2) = w1;
      }
    }
    // same-wave readback (program-order DS within a wave; compiler inserts waits)
    #pragma unroll
    for(int p=0;p<16;p++){
      int dl = p*4 + (lane>>4);
      us4 vv = *(const us4*)(ep + dl*64 + (lane&15)*4);
      *(us4*)(vt + (bh*64 + dl)*2048 + nn0 + (lane&15)*4) = vv;
    }
  }
}

// ---------------- GEMM2 v2: 64x128 tiles, grid (64,8)=512 blocks -> 2 blocks/CU ----
__global__ __launch_bounds__(256) void gemm_proj(const unsigned short* __restrict__ y,
                                                 const unsigned short* __restrict__ Wt,
                                                 const float* __restrict__ bp,
                                                 float* __restrict__ out)
{
  __shared__ __attribute__((aligned(16))) unsigned short As[64*BK];    // 8KB
  __shared__ __attribute__((aligned(16))) unsigned short Bs[128*BK];   // 16KB
  const int bm = blockIdx.x, bn = blockIdx.y;
  const int t = threadIdx.x, lane = t&63, wid = t>>6;
  const int wm = wid>>1, wn = wid&1;
  const int lq = lane&15, lh = lane>>4;
  const int rowA0 = bm*64, rowB0 = bn*128;
  const f32x4 Z = {0.f,0.f,0.f,0.f};
  f32x4 acc[2][4];
  #pragma unroll
  for(int m=0;m<2;m++)
    #pragma unroll
    for(int n=0;n<4;n++) acc[m][n] = Z;

  for(int kt=0; kt<1024; kt+=BK){
    __syncthreads();
    #pragma unroll
    for(int j=0;j<2;j++){          // A: 512 chunks = 64 rows x 8
      int idx = t + 256*j;
      int row = idx >> 3;
      int ls  = (idx & 7) ^ (row & 7);
      glds16(y + (size_t)(rowA0 + row)*1024 + kt + ls*8, As + (size_t)(wid*64 + 256*j)*8);
    }
    #pragma unroll
    for(int j=0;j<4;j++){          // B: 1024 chunks = 128 rows x 8
      int idx = t + 256*j;
      int row = idx >> 3;
      int ls  = (idx & 7) ^ (row & 7);
      glds16(Wt + (size_t)(rowB0 + row)*1024 + kt + ls*8, Bs + (size_t)(wid*64 + 256*j)*8);
    }
    __syncthreads();
    #pragma unroll
    for(int ks=0; ks<2; ks++){
      bf16x8 af[2], bfr[4];
      #pragma unroll
      for(int m=0;m<2;m++){
        int row = wm*32 + m*16 + lq;
        int sl  = (ks*4 + lh) ^ (row&7);
        af[m] = *(const bf16x8*)(As + row*64 + sl*8);
      }
      #pragma unroll
      for(int n=0;n<4;n++){
        int row = wn*64 + n*16 + lq;
        int sl  = (ks*4 + lh) ^ (row&7);
        bfr[n] = *(const bf16x8*)(Bs + row*64 + sl*8);
      }
      #pragma unroll
      for(int m=0;m<2;m++)
        #pragma unroll
        for(int n=0;n<4;n++)
          acc[m][n] = __builtin_amdgcn_mfma_f32_16x16x32_bf16(af[m], bfr[n], acc[m][n], 0, 0, 0);
    }
  }

  #pragma unroll
  for(int m=0;m<2;m++)
    #pragma unroll
    for(int n=0;n<4;n++){
      int col = bn*128 + wn*64 + n*16 + lq;
      float bias = bp[col];
      #pragma unroll
      for(int r=0;r<4;r++){
        int row = bm*64 + wm*32 + m*16 + lh*4 + r;
        out[(size_t)row*1024 + col] = acc[m][n][r] + bias;
      }
    }
}

// ---------------- flash attention v6 (R13-exact, proven 62us): 64 q-rows/block ----
__global__ __launch_bounds__(256, 4) void attn_k(const unsigned short* __restrict__ qg,
                                                 const unsigned short* __restrict__ kg,
                                                 const unsigned short* __restrict__ vtg,
                                                 unsigned short* __restrict__ y)
{
  __shared__ __attribute__((aligned(16))) unsigned short Ks[2][64*64];  // [kv][d] swizzled
  __shared__ __attribute__((aligned(16))) unsigned short VT[2][64*64];  // [d][kv] swizzled
  __shared__ __attribute__((aligned(16))) unsigned short Ps[4][16*64];  // per-wave P^T, swizzled

  const int bh = blockIdx.x;      // b*16 + h
  const int qt = blockIdx.y;      // 0..31
  const int b  = bh >> 4, h = bh & 15;
  const unsigned short* qh = qg  + (size_t)bh*2048*64;
  const unsigned short* kh = kg  + (size_t)bh*2048*64;
  const unsigned short* vh = vtg + (size_t)bh*64*2048;

  const int t = threadIdx.x, lane = t & 63, wid = t >> 6;
  const int q0 = qt*64 + wid*16;
  const int lq = lane & 15;
  const int lh = lane >> 4;                 // 16-lane group 0..3
  const float C1 = 0.18033688011112042f;    // (1/8) * log2(e)

  // Q fragments (B-operand pattern) held in registers
  bf16x8 aq[2];
  #pragma unroll
  for(int ks=0;ks<2;ks++){
    int row = q0 + lq;
    aq[ks] = *(const bf16x8*)(qh + (size_t)row*64 + ks*32 + lh*8);
  }

  const f32x4 Z = {0.f,0.f,0.f,0.f};
  f32x4 accT[4];                    // O^T tiles per d-subtile
  #pragma unroll
  for(int df=0;df<4;df++) accT[df] = Z;
  float lpart = 0.f;                // per-lane partial row-sum

  // prologue: stage tile 0 into buffer 0
  #pragma unroll
  for(int j=0;j<2;j++){
    int idx = t + 256*j;
    int row = idx >> 3;
    int ls  = (idx & 7) ^ (row & 7);
    glds16(kh + (size_t)row*64 + ls*8, &Ks[0][0] + (wid*64 + 256*j)*8);
    glds16(vh + (size_t)row*2048 + ls*8, &VT[0][0] + (wid*64 + 256*j)*8);
  }
  __syncthreads();

  for(int it=0; it<32; ++it){
    const int cur = it & 1, nxt = cur ^ 1;
    // prefetch next tile (loads stay in flight across the compute phase)
    if(it < 31){
      int kvn = (it+1)*64;
      #pragma unroll
      for(int j=0;j<2;j++){
        int idx = t + 256*j;
        int row = idx >> 3;
        int ls  = (idx & 7) ^ (row & 7);
        glds16(kh + (size_t)(kvn+row)*64 + ls*8, &Ks[nxt][0] + (wid*64 + 256*j)*8);
        glds16(vh + (size_t)row*2048 + kvn + ls*8, &VT[nxt][0] + (wid*64 + 256*j)*8);
      }
    }

    // S^T = mfma(K, Q)
    f32x4 st[4];
    #pragma unroll
    for(int nc=0;nc<4;nc++) st[nc] = Z;
    __builtin_amdgcn_s_setprio(1);
    #pragma unroll
    for(int ks=0;ks<2;ks++){
      bf16x8 bk[4];
      #pragma unroll
      for(int nc=0;nc<4;nc++){
        int kvr = nc*16 + lq;
        int sl  = (ks*4 + lh) ^ (kvr&7);
        bk[nc] = *(const bf16x8*)(&Ks[cur][0] + kvr*64 + sl*8);
      }
      #pragma unroll
      for(int nc=0;nc<4;nc++)
        st[nc] = __builtin_amdgcn_mfma_f32_16x16x32_bf16(bk[nc], aq[ks], st[nc], 0,0,0);
    }
    __builtin_amdgcn_s_setprio(0);

    // softmax numerator p = 2^(s*C1): raw v_exp + cvt_pk pack + swizzled 8B LDS write
    {
      float rs = 0.f;
      unsigned short* pr = &Ps[wid][0] + lq*64;   // 128B row
      #pragma unroll
      for(int nc=0;nc<4;nc++){
        float p0 = __builtin_amdgcn_exp2f(st[nc][0]*C1);
        float p1 = __builtin_amdgcn_exp2f(st[nc][1]*C1);
        float p2 = __builtin_amdgcn_exp2f(st[nc][2]*C1);
        float p3 = __builtin_amdgcn_exp2f(st[nc][3]*C1);
        rs += (p0+p1)+(p2+p3);
        unsigned w0, w1;
        asm("v_cvt_pk_bf16_f32 %0, %1, %2" : "=v"(w0) : "v"(p0), "v"(p1));
        asm("v_cvt_pk_bf16_f32 %0, %1, %2" : "=v"(w1) : "v"(p2), "v"(p3));
        int g    = 2*nc + (lh>>1);
        int phys = g ^ (lane&7);
        unsigned* dst = (unsigned*)(pr + phys*8 + (lh&1)*4);
        dst[0] = w0; dst[1] = w1;
      }
      lpart += rs;
    }

    // O^T += mfma(V^T, P^T)  (own-wave Ps region; same-wave DS ordering)
    __builtin_amdgcn_s_setprio(1);
    #pragma unroll
    for(int ks=0;ks<2;ks++){
      bf16x8 bv[4], pa;
      #pragma unroll
      for(int df=0;df<4;df++){
        int dr = df*16 + lq;
        int sl = (ks*4 + lh) ^ (dr&7);
        bv[df] = *(const bf16x8*)(&VT[cur][0] + dr*64 + sl*8);
      }
      {
        int g    = 4*ks + lh;
        int phys = g ^ (lane&7);
        pa = *(const bf16x8*)(&Ps[wid][0] + lq*64 + phys*8);
      }
      #pragma unroll
      for(int df=0;df<4;df++)
        accT[df] = __builtin_amdgcn_mfma_f32_16x16x32_bf16(bv[df], pa, accT[df], 0,0,0);
    }
    __builtin_amdgcn_s_setprio(0);

    __syncthreads();   // drains this wave's prefetch glds + all waves' LDS reads of cur
  }

  // epilogue: one cross-lane sum, then normalize + store
  float ls = lpart;
  ls += __shfl_xor(ls, 16, 64);
  ls += __shfl_xor(ls, 32, 64);
  float rl = 1.0f / ls;
  int row = q0 + lq;
  #pragma unroll
  for(int df=0;df<4;df++){
    us4 o;
    o.x = f2b(accT[df][0] * rl);
    o.y = f2b(accT[df][1] * rl);
    o.z = f2b(accT[df][2] * rl);
    o.w = f2b(accT[df][3] * rl);
    *(us4*)(y + ((size_t)b*2048 + row)*1024 + h*64 + df*16 + lh*4) = o;
  }
}

extern "C" void kernel_launch(void* const* d_in, const int* in_sizes, int n_in,
                              void* d_out, int out_size, void* d_ws, size_t ws_size,
                              hipStream_t stream) {
  const float* x     = (const float*)d_in[0];
  const float* wqkv  = (const float*)d_in[1];
  const float* bqkv  = (const float*)d_in[2];
  const float* wproj = (const float*)d_in[3];
  const float* bproj = (const float*)d_in[4];
  float* out = (float*)d_out;

  char* ws = (char*)d_ws;
  unsigned short* Wt1 = (unsigned short*)ws;  ws += (size_t)3072*1024*2;
  unsigned short* Wt2 = (unsigned short*)ws;  ws += (size_t)1024*1024*2;
  unsigned short* xb  = (unsigned short*)ws;  ws += (size_t)2*2048*1024*2;
  unsigned short* q   = (unsigned short*)ws;  ws += (size_t)2*16*2048*64*2;
  unsigned short* k   = (unsigned short*)ws;  ws += (size_t)2*16*2048*64*2;
  unsigned short* vt  = (unsigned short*)ws;  ws += (size_t)2*16*2048*64*2;
  unsigned short* y   = (unsigned short*)ws;  ws += (size_t)2*2048*1024*2;

  prep_k    <<<3072, 256, 0, stream>>>(x, xb, wqkv, Wt1, wproj, Wt2);
  gemm_qkv  <<<dim3(32,24), 256, 0, stream>>>(xb, Wt1, bqkv, q, k, vt);
  attn_k    <<<dim3(32,32), 256, 0, stream>>>(q, k, vt, y);
  gemm_proj <<<dim3(64, 8), 256, 0, stream>>>(y, Wt2, bproj, out);
}